// Round 1
// baseline (20356.554 us; speedup 1.0000x reference)
//
#include <hip/hip_runtime.h>
#include <math.h>

#define DMODEL 768
#define DEPTH 12
#define HEADS 12
#define HEADD 64
#define NTOK 197
#define BATCH 32
#define NPATCH 196
#define MTOK (BATCH * NTOK)    // 6304
#define MPAT (BATCH * NPATCH)  // 6272
#define QKVD 2304
#define MLPD 3072

// ---------------- block-wide reductions (256 threads = 4 waves) ----------------
__device__ __forceinline__ float blk_red_sum(float v, float* red) {
#pragma unroll
  for (int o = 32; o; o >>= 1) v += __shfl_xor(v, o);
  __syncthreads();
  if ((threadIdx.x & 63) == 0) red[threadIdx.x >> 6] = v;
  __syncthreads();
  return red[0] + red[1] + red[2] + red[3];
}
__device__ __forceinline__ float blk_red_max(float v, float* red) {
#pragma unroll
  for (int o = 32; o; o >>= 1) v = fmaxf(v, __shfl_xor(v, o));
  __syncthreads();
  if ((threadIdx.x & 63) == 0) red[threadIdx.x >> 6] = v;
  __syncthreads();
  return fmaxf(fmaxf(red[0], red[1]), fmaxf(red[2], red[3]));
}

__device__ __forceinline__ float gelu_f(float x) {
  return 0.5f * x * (1.f + erff(x * 0.70710678118654752440f));
}

// ---------------- im2col for patch embedding ----------------
__global__ __launch_bounds__(256) void im2col(const float* __restrict__ x,
                                              float* __restrict__ col) {
  int idx = blockIdx.x * 256 + threadIdx.x;
  if (idx >= MPAT * DMODEL) return;
  int kk = idx % DMODEL;        // ch*256 + i*16 + j
  int m = idx / DMODEL;         // b*196 + p
  int bb = m / NPATCH, p = m % NPATCH;
  int ph = p / 14, pw = p % 14;
  int ch = kk >> 8, rem = kk & 255;
  int i = rem >> 4, j = rem & 15;
  col[idx] = x[(((size_t)bb * 3 + ch) * 224 + ph * 16 + i) * 224 + pw * 16 + j];
}

// ---------------- token assembly: cls + patches + pos ----------------
__global__ __launch_bounds__(256) void assemble(const float* __restrict__ pat,
                                                const float* __restrict__ cls,
                                                const float* __restrict__ pos,
                                                float* __restrict__ tokens) {
  int idx = blockIdx.x * 256 + threadIdx.x;
  if (idx >= MTOK * DMODEL) return;
  int c = idx % DMODEL;
  int t = idx / DMODEL;
  int bb = t / NTOK, n = t % NTOK;
  float v;
  if (n == 0)
    v = cls[c];
  else
    v = pat[((size_t)bb * NPATCH + (n - 1)) * DMODEL + c];
  tokens[idx] = v + pos[n * DMODEL + c];
}

// ---------------- LayerNorm over 768, one block per token ----------------
__global__ __launch_bounds__(256) void layernorm(const float* __restrict__ in,
                                                 const float* __restrict__ w,
                                                 const float* __restrict__ b,
                                                 float* __restrict__ out) {
  __shared__ float red[4];
  const int t = blockIdx.x, tid = threadIdx.x;
  const float* r = in + (size_t)t * DMODEL;
  float x0 = r[tid], x1 = r[tid + 256], x2 = r[tid + 512];
  float mu = blk_red_sum(x0 + x1 + x2, red) * (1.f / 768.f);
  float d0 = x0 - mu, d1 = x1 - mu, d2 = x2 - mu;
  float var = blk_red_sum(d0 * d0 + d1 * d1 + d2 * d2, red) * (1.f / 768.f);
  float is = rsqrtf(var + 1e-6f);
  float* o = out + (size_t)t * DMODEL;
  o[tid] = d0 * is * w[tid] + b[tid];
  o[tid + 256] = d1 * is * w[tid + 256] + b[tid + 256];
  o[tid + 512] = d2 * is * w[tid + 512] + b[tid + 512];
}

// ---------------- generic f32 NT GEMM: C[m,n] (+)= sum_k A[m,k]*B[n,k] ----------------
// mode 0: C = acc + bias ; mode 1: C += acc + bias ; mode 2: C = gelu(acc + bias)
__global__ __launch_bounds__(256) void gemm_nt(const float* __restrict__ A,
                                               const float* __restrict__ B,
                                               const float* __restrict__ bias,
                                               float* __restrict__ C,
                                               int M, int N, int K, int mode) {
  __shared__ float As[16][68];
  __shared__ float Bs[16][68];
  const int tid = threadIdx.x;
  const int m0 = blockIdx.x * 64, n0 = blockIdx.y * 64;
  const int tx = tid & 15, ty = tid >> 4;
  const int lr = tid >> 2, lc = (tid & 3) * 4;
  float acc[4][4] = {};
  const float* Ap = A + (size_t)(m0 + lr) * K + lc;
  const float* Bp = B + (size_t)(n0 + lr) * K + lc;
  const bool aok = (m0 + lr) < M;
  for (int k0 = 0; k0 < K; k0 += 16) {
    float4 av = make_float4(0.f, 0.f, 0.f, 0.f);
    if (aok) av = *(const float4*)(Ap + k0);
    float4 bv = *(const float4*)(Bp + k0);
    As[lc + 0][lr] = av.x; As[lc + 1][lr] = av.y;
    As[lc + 2][lr] = av.z; As[lc + 3][lr] = av.w;
    Bs[lc + 0][lr] = bv.x; Bs[lc + 1][lr] = bv.y;
    Bs[lc + 2][lr] = bv.z; Bs[lc + 3][lr] = bv.w;
    __syncthreads();
#pragma unroll
    for (int kk = 0; kk < 16; ++kk) {
      float4 af = *(const float4*)&As[kk][ty * 4];
      float4 bf = *(const float4*)&Bs[kk][tx * 4];
      float ar[4] = {af.x, af.y, af.z, af.w};
      float br[4] = {bf.x, bf.y, bf.z, bf.w};
#pragma unroll
      for (int i = 0; i < 4; ++i)
#pragma unroll
        for (int j = 0; j < 4; ++j) acc[i][j] = fmaf(ar[i], br[j], acc[i][j]);
    }
    __syncthreads();
  }
  float4 bvv = make_float4(0.f, 0.f, 0.f, 0.f);
  if (bias) bvv = *(const float4*)&bias[n0 + tx * 4];
#pragma unroll
  for (int i = 0; i < 4; ++i) {
    int m = m0 + ty * 4 + i;
    if (m >= M) break;
    float4 r = make_float4(acc[i][0] + bvv.x, acc[i][1] + bvv.y,
                           acc[i][2] + bvv.z, acc[i][3] + bvv.w);
    float* cp = C + (size_t)m * N + n0 + tx * 4;
    if (mode == 1) {
      float4 o = *(const float4*)cp;
      r.x += o.x; r.y += o.y; r.z += o.z; r.w += o.w;
    } else if (mode == 2) {
      r.x = gelu_f(r.x); r.y = gelu_f(r.y); r.z = gelu_f(r.z); r.w = gelu_f(r.w);
    }
    *(float4*)cp = r;
  }
}

// ---------------- probe attention + top-k, one block per batch ----------------
__global__ __launch_bounds__(256) void probe_topk(const float* __restrict__ qkv,
                                                  const int* __restrict__ kpptr,
                                                  int* __restrict__ topk) {
  __shared__ float qrow[64];
  __shared__ float s[NTOK];
  __shared__ float accsc[NTOK];
  __shared__ float red[4];
  const int b = blockIdx.x, tid = threadIdx.x;
  const size_t row0 = (size_t)b * NTOK * QKVD;
  for (int k = tid; k < NTOK; k += 256) accsc[k] = 0.f;
  for (int h = 0; h < HEADS; ++h) {
    __syncthreads();
    if (tid < 64) qrow[tid] = qkv[row0 + h * HEADD + tid];
    __syncthreads();
    for (int k = tid; k < NTOK; k += 256) {
      const float* kr = qkv + row0 + (size_t)k * QKVD + DMODEL + h * HEADD;
      float dot = 0.f;
#pragma unroll 8
      for (int d = 0; d < 64; ++d) dot = fmaf(qrow[d], kr[d], dot);
      s[k] = dot * 0.125f;
    }
    __syncthreads();
    float mx = -1e30f;
    for (int k = tid; k < NTOK; k += 256) mx = fmaxf(mx, s[k]);
    mx = blk_red_max(mx, red);
    float sm = 0.f;
    for (int k = tid; k < NTOK; k += 256) sm += expf(s[k] - mx);
    sm = blk_red_sum(sm, red);
    float inv = 1.f / sm;
    for (int k = tid; k < NTOK; k += 256) accsc[k] += expf(s[k] - mx) * inv;
  }
  __syncthreads();
  if (tid == 0) {
    int kpn = kpptr[0];
    if (kpn < 0) kpn = 0;
    if (kpn > 8) kpn = 8;
    for (int j = 0; j < kpn; ++j) {
      float best = -1e30f;
      int bi = 1;
      for (int k = 1; k < NTOK; ++k) {
        if (accsc[k] > best) { best = accsc[k]; bi = k; }
      }
      topk[b * 8 + j] = bi;
      accsc[bi] = -2e30f;
    }
    for (int j = kpn; j < 8; ++j) topk[b * 8 + j] = -1;
  }
}

// ---------------- fused attention, one block per (b, h) ----------------
__global__ __launch_bounds__(256) void attn_fused(
    const float* __restrict__ qkv, const float* __restrict__ prompt_k,
    const float* __restrict__ prompt_v, const float* __restrict__ pk,
    const float* __restrict__ pv, const int* __restrict__ topk,
    const int* __restrict__ kpptr, float* __restrict__ outp) {
  __shared__ float kmod_t[64 * NTOK];  // [d][k]  (d-major: conflict-free score reads)
  __shared__ float pbuf[16][NTOK];
  __shared__ float qbuf[4][64];
  __shared__ float selb[NTOK];
  const int bh = blockIdx.x;
  const int b = bh / HEADS, h = bh % HEADS;
  const int tid = threadIdx.x, w = tid >> 6, lane = tid & 63;
  int kpn = kpptr[0];
  if (kpn < 0) kpn = 0;
  if (kpn > 8) kpn = 8;
  for (int k = tid; k < NTOK; k += 256) {
    float sl = 0.f;
    for (int j = 0; j < kpn; ++j)
      if (topk[b * 8 + j] == k) sl = 1.f;
    selb[k] = sl;
  }
  __syncthreads();
  const size_t row0 = (size_t)b * NTOK * QKVD;
  const float* kbase = qkv + row0 + DMODEL + h * HEADD;
  for (int idx = tid; idx < NTOK * 64; idx += 256) {
    int kk = idx >> 6, d = idx & 63;
    float v = kbase[(size_t)kk * QKVD + d];
    if (kk == 0) v += prompt_k[h * HEADD + d];
    v += selb[kk] * pk[h * HEADD + d];
    kmod_t[d * NTOK + kk] = v;
  }
  __syncthreads();
  const float pvp = prompt_v[h * HEADD + lane];
  const float pvv = pv[h * HEADD + lane];
  const float* qbase = qkv + row0 + h * HEADD;
  const float* vbase = qkv + row0 + 2 * DMODEL + h * HEADD;
  float* obase = outp + (size_t)b * NTOK * DMODEL + h * HEADD;

  for (int r0 = 0; r0 < NTOK; r0 += 16) {
#pragma unroll
    for (int rr = 0; rr < 4; ++rr) {
      int q = r0 + w * 4 + rr;
      if (q >= NTOK) continue;
      qbuf[w][lane] = qbase[(size_t)q * QKVD + lane];
      float sc[4];
#pragma unroll
      for (int j = 0; j < 4; ++j) {
        int k = lane + j * 64;
        if (k < NTOK) {
          float dot = 0.f;
#pragma unroll 8
          for (int d = 0; d < 64; ++d)
            dot = fmaf(qbuf[w][d], kmod_t[d * NTOK + k], dot);
          sc[j] = dot * 0.125f;
        } else {
          sc[j] = -1e30f;
        }
      }
      float mx = fmaxf(fmaxf(sc[0], sc[1]), fmaxf(sc[2], sc[3]));
#pragma unroll
      for (int o = 32; o; o >>= 1) mx = fmaxf(mx, __shfl_xor(mx, o));
      float pr[4];
      float sm = 0.f;
#pragma unroll
      for (int j = 0; j < 4; ++j) {
        pr[j] = __expf(sc[j] - mx);
        if (lane + j * 64 >= NTOK) pr[j] = 0.f;
        sm += pr[j];
      }
#pragma unroll
      for (int o = 32; o; o >>= 1) sm += __shfl_xor(sm, o);
      float inv = 1.f / sm;
#pragma unroll
      for (int j = 0; j < 4; ++j) {
        int k = lane + j * 64;
        if (k < NTOK) pbuf[w * 4 + rr][k] = pr[j] * inv;
      }
    }
    // PV for this wave's 4 rows (lane == d)
    float a0 = 0.f, a1 = 0.f, a2 = 0.f, a3 = 0.f;
    for (int k = 0; k < NTOK; ++k) {
      float vv = vbase[(size_t)k * QKVD + lane];
      if (k == 0) vv += pvp;
      vv += selb[k] * pvv;
      a0 = fmaf(pbuf[w * 4 + 0][k], vv, a0);
      a1 = fmaf(pbuf[w * 4 + 1][k], vv, a1);
      a2 = fmaf(pbuf[w * 4 + 2][k], vv, a2);
      a3 = fmaf(pbuf[w * 4 + 3][k], vv, a3);
    }
    int q0 = r0 + w * 4;
    if (q0 + 0 < NTOK) obase[(size_t)(q0 + 0) * DMODEL + lane] = a0;
    if (q0 + 1 < NTOK) obase[(size_t)(q0 + 1) * DMODEL + lane] = a1;
    if (q0 + 2 < NTOK) obase[(size_t)(q0 + 2) * DMODEL + lane] = a2;
    if (q0 + 3 < NTOK) obase[(size_t)(q0 + 3) * DMODEL + lane] = a3;
  }
}

// ---------------- host ----------------
extern "C" void kernel_launch(void* const* d_in, const int* in_sizes, int n_in,
                              void* d_out, int out_size, void* d_ws, size_t ws_size,
                              hipStream_t stream) {
  const float* x = (const float*)d_in[0];
  const float* patch_w = (const float*)d_in[1];
  const float* patch_b = (const float*)d_in[2];
  const float* cls_tok = (const float*)d_in[3];
  const float* pos_emb = (const float*)d_in[4];
  const float* ln1_w = (const float*)d_in[5];
  const float* ln1_b = (const float*)d_in[6];
  const float* qkv_w = (const float*)d_in[7];
  const float* qkv_b = (const float*)d_in[8];
  const float* proj_w = (const float*)d_in[9];
  const float* proj_b = (const float*)d_in[10];
  const float* pk_par = (const float*)d_in[11];
  const float* pv_par = (const float*)d_in[12];
  const float* pr_k = (const float*)d_in[13];
  const float* pr_v = (const float*)d_in[14];
  const float* ln2_w = (const float*)d_in[15];
  const float* ln2_b = (const float*)d_in[16];
  const float* fc1_w = (const float*)d_in[17];
  const float* fc1_b = (const float*)d_in[18];
  const float* fc2_w = (const float*)d_in[19];
  const float* fc2_b = (const float*)d_in[20];
  const float* norm_w = (const float*)d_in[21];
  const float* norm_b = (const float*)d_in[22];
  const int* kp = (const int*)d_in[23];

  float* tokens = (float*)d_ws;
  float* bufh = tokens + (size_t)MTOK * DMODEL;
  float* bufbig = bufh + (size_t)MTOK * DMODEL;
  int* topk = (int*)(bufbig + (size_t)MTOK * MLPD);

  // patch embedding: im2col -> GEMM(+patch_b) -> assemble tokens (+cls,+pos)
  im2col<<<(MPAT * DMODEL + 255) / 256, 256, 0, stream>>>(x, bufbig);
  gemm_nt<<<dim3(MPAT / 64, DMODEL / 64), 256, 0, stream>>>(
      bufbig, patch_w, patch_b, bufh, MPAT, DMODEL, DMODEL, 0);
  assemble<<<(MTOK * DMODEL + 255) / 256, 256, 0, stream>>>(bufh, cls_tok,
                                                            pos_emb, tokens);

  const int mt = (MTOK + 63) / 64;
  for (int l = 0; l < DEPTH; ++l) {
    layernorm<<<MTOK, 256, 0, stream>>>(tokens, ln1_w + l * DMODEL,
                                        ln1_b + l * DMODEL, bufh);
    gemm_nt<<<dim3(mt, QKVD / 64), 256, 0, stream>>>(
        bufh, qkv_w + (size_t)l * QKVD * DMODEL, qkv_b + l * QKVD, bufbig,
        MTOK, QKVD, DMODEL, 0);
    probe_topk<<<BATCH, 256, 0, stream>>>(bufbig, kp, topk);
    attn_fused<<<BATCH * HEADS, 256, 0, stream>>>(
        bufbig, pr_k + l * HEADS * HEADD, pr_v + l * HEADS * HEADD,
        pk_par + l * HEADS * HEADD, pv_par + l * HEADS * HEADD, topk, kp, bufh);
    gemm_nt<<<dim3(mt, DMODEL / 64), 256, 0, stream>>>(
        bufh, proj_w + (size_t)l * DMODEL * DMODEL, proj_b + l * DMODEL, tokens,
        MTOK, DMODEL, DMODEL, 1);
    layernorm<<<MTOK, 256, 0, stream>>>(tokens, ln2_w + l * DMODEL,
                                        ln2_b + l * DMODEL, bufh);
    gemm_nt<<<dim3(mt, MLPD / 64), 256, 0, stream>>>(
        bufh, fc1_w + (size_t)l * MLPD * DMODEL, fc1_b + l * MLPD, bufbig,
        MTOK, MLPD, DMODEL, 2);
    gemm_nt<<<dim3(mt, DMODEL / 64), 256, 0, stream>>>(
        bufbig, fc2_w + (size_t)l * DMODEL * MLPD, fc2_b + l * DMODEL, tokens,
        MTOK, DMODEL, MLPD, 1);
  }
  layernorm<<<MTOK, 256, 0, stream>>>(tokens, norm_w, norm_b, (float*)d_out);
}

// Round 2
// 7998.646 us; speedup vs baseline: 2.5450x; 2.5450x over previous
//
#include <hip/hip_runtime.h>
#include <math.h>

#define DMODEL 768
#define DEPTH 12
#define HEADS 12
#define HEADD 64
#define NTOK 197
#define BATCH 32
#define NPATCH 196
#define MTOK (BATCH * NTOK)    // 6304
#define MPAT (BATCH * NPATCH)  // 6272
#define QKVD 2304
#define MLPD 3072

typedef unsigned short u16;
typedef __attribute__((ext_vector_type(8))) short bf16x8;
typedef __attribute__((ext_vector_type(4))) float f32x4;

// weight staging offsets (elements) inside per-layer bf16 buffer
#define OFF_QKV 0
#define OFF_PROJ (QKVD * DMODEL)                    // 1769472
#define OFF_FC1 (OFF_PROJ + DMODEL * DMODEL)       // 2359296
#define OFF_FC2 (OFF_FC1 + MLPD * DMODEL)          // 4718592
#define WTOTAL (OFF_FC2 + DMODEL * MLPD)           // 7077888

__device__ __forceinline__ u16 bf16r(float x) {
  union { float f; unsigned u; } c; c.f = x;
  unsigned u = c.u + 0x7FFF + ((c.u >> 16) & 1);
  return (u16)(u >> 16);
}
__device__ __forceinline__ float gelu_f(float x) {
  return 0.5f * x * (1.f + erff(x * 0.70710678118654752440f));
}
__device__ __forceinline__ void gload16(const void* g, void* l) {
  __builtin_amdgcn_global_load_lds(
      (const __attribute__((address_space(1))) void*)g,
      (__attribute__((address_space(3))) void*)l, 16, 0, 0);
}

// ---------------- block-wide reductions (256 threads = 4 waves) ----------------
__device__ __forceinline__ float blk_red_sum(float v, float* red) {
#pragma unroll
  for (int o = 32; o; o >>= 1) v += __shfl_xor(v, o);
  __syncthreads();
  if ((threadIdx.x & 63) == 0) red[threadIdx.x >> 6] = v;
  __syncthreads();
  return red[0] + red[1] + red[2] + red[3];
}
__device__ __forceinline__ float blk_red_max(float v, float* red) {
#pragma unroll
  for (int o = 32; o; o >>= 1) v = fmaxf(v, __shfl_xor(v, o));
  __syncthreads();
  if ((threadIdx.x & 63) == 0) red[threadIdx.x >> 6] = v;
  __syncthreads();
  return fmaxf(fmaxf(red[0], red[1]), fmaxf(red[2], red[3]));
}

// ---------------- f32 -> bf16 conversions ----------------
__global__ __launch_bounds__(256) void convert_bf16(const float* __restrict__ in,
                                                    u16* __restrict__ out, int n) {
  int i = (blockIdx.x * 256 + threadIdx.x) * 4;
  if (i >= n) return;
  float4 v = *(const float4*)(in + i);
  ushort4 o;
  o.x = bf16r(v.x); o.y = bf16r(v.y); o.z = bf16r(v.z); o.w = bf16r(v.w);
  *(ushort4*)(out + i) = o;
}

// all 4 weight matrices of one layer -> bf16 staging buffer
__global__ __launch_bounds__(256) void convert_layer_w(
    const float* __restrict__ qkv_w, const float* __restrict__ proj_w,
    const float* __restrict__ fc1_w, const float* __restrict__ fc2_w,
    u16* __restrict__ wbuf) {
  int i = (blockIdx.x * 256 + threadIdx.x) * 4;
  if (i >= WTOTAL) return;
  const float* s;
  if (i < OFF_PROJ) s = qkv_w + i;
  else if (i < OFF_FC1) s = proj_w + (i - OFF_PROJ);
  else if (i < OFF_FC2) s = fc1_w + (i - OFF_FC1);
  else s = fc2_w + (i - OFF_FC2);
  float4 v = *(const float4*)s;
  ushort4 o;
  o.x = bf16r(v.x); o.y = bf16r(v.y); o.z = bf16r(v.z); o.w = bf16r(v.w);
  *(ushort4*)(wbuf + i) = o;
}

// ---------------- im2col for patch embedding (bf16 out) ----------------
__global__ __launch_bounds__(256) void im2col(const float* __restrict__ x,
                                              u16* __restrict__ col) {
  int idx = blockIdx.x * 256 + threadIdx.x;
  if (idx >= MPAT * DMODEL) return;
  int kk = idx % DMODEL;        // ch*256 + i*16 + j
  int m = idx / DMODEL;         // b*196 + p
  int bb = m / NPATCH, p = m % NPATCH;
  int ph = p / 14, pw = p % 14;
  int ch = kk >> 8, rem = kk & 255;
  int i = rem >> 4, j = rem & 15;
  col[idx] = bf16r(x[(((size_t)bb * 3 + ch) * 224 + ph * 16 + i) * 224 + pw * 16 + j]);
}

// ---------------- token assembly: cls + patches + pos ----------------
__global__ __launch_bounds__(256) void assemble(const float* __restrict__ pat,
                                                const float* __restrict__ cls,
                                                const float* __restrict__ pos,
                                                float* __restrict__ tokens) {
  int idx = blockIdx.x * 256 + threadIdx.x;
  if (idx >= MTOK * DMODEL) return;
  int c = idx % DMODEL;
  int t = idx / DMODEL;
  int bb = t / NTOK, n = t % NTOK;
  float v;
  if (n == 0) v = cls[c];
  else v = pat[((size_t)bb * NPATCH + (n - 1)) * DMODEL + c];
  tokens[idx] = v + pos[n * DMODEL + c];
}

// ---------------- LayerNorm over 768, one block per token ----------------
template <bool BF16OUT>
__global__ __launch_bounds__(256) void layernorm(const float* __restrict__ in,
                                                 const float* __restrict__ w,
                                                 const float* __restrict__ b,
                                                 void* __restrict__ outp) {
  __shared__ float red[4];
  const int t = blockIdx.x, tid = threadIdx.x;
  const float* r = in + (size_t)t * DMODEL;
  float x0 = r[tid], x1 = r[tid + 256], x2 = r[tid + 512];
  float mu = blk_red_sum(x0 + x1 + x2, red) * (1.f / 768.f);
  float d0 = x0 - mu, d1 = x1 - mu, d2 = x2 - mu;
  float var = blk_red_sum(d0 * d0 + d1 * d1 + d2 * d2, red) * (1.f / 768.f);
  float is = rsqrtf(var + 1e-6f);
  float v0 = d0 * is * w[tid] + b[tid];
  float v1 = d1 * is * w[tid + 256] + b[tid + 256];
  float v2 = d2 * is * w[tid + 512] + b[tid + 512];
  if (BF16OUT) {
    u16* o = (u16*)outp + (size_t)t * DMODEL;
    o[tid] = bf16r(v0); o[tid + 256] = bf16r(v1); o[tid + 512] = bf16r(v2);
  } else {
    float* o = (float*)outp + (size_t)t * DMODEL;
    o[tid] = v0; o[tid + 256] = v1; o[tid + 512] = v2;
  }
}

// ---------------- bf16 MFMA NT GEMM: C[m,n] = sum_k A[m,k]*B[n,k] + bias[n] ----
// MODE 0: C(f32) = acc+bias ; MODE 1: C(f32) += acc+bias ; MODE 2: C(bf16) = gelu
// 128x128 tile, BK=32, 4 waves (2x2 of 64x64), mfma_f32_16x16x32_bf16
template <int MODE>
__global__ __launch_bounds__(256) void gemm_bf16(const u16* __restrict__ A,
                                                 const u16* __restrict__ B,
                                                 const float* __restrict__ bias,
                                                 void* __restrict__ C,
                                                 int M, int N, int K) {
  __shared__ u16 As[128 * 32];
  __shared__ u16 Bs[128 * 32];
  const int tid = threadIdx.x;
  const int w = tid >> 6, lane = tid & 63;
  const int m0 = blockIdx.x * 128, n0 = blockIdx.y * 128;
  const int wr = (w >> 1) * 64, wc = (w & 1) * 64;
  f32x4 acc[4][4] = {};

  // staging: thread t covers row (i*64 + t/4), k-elems [(t&3)*8, +8) of the tile
  const int srow = tid >> 2;
  const int scol = (tid & 3) * 8;
  int ar0 = m0 + srow;       if (ar0 >= M) ar0 = M - 1;
  int ar1 = m0 + 64 + srow;  if (ar1 >= M) ar1 = M - 1;
  const u16* Ag0 = A + (size_t)ar0 * K + scol;
  const u16* Ag1 = A + (size_t)ar1 * K + scol;
  const u16* Bg0 = B + (size_t)(n0 + srow) * K + scol;
  const u16* Bg1 = B + (size_t)(n0 + 64 + srow) * K + scol;
  u16* AsW0 = As + w * 512;          // issue 0: bytes [w*1024, +1024)
  u16* AsW1 = As + 2048 + w * 512;   // issue 1
  u16* BsW0 = Bs + w * 512;
  u16* BsW1 = Bs + 2048 + w * 512;

  const int kq = (lane >> 4) * 8;    // fragment k-offset
  const int fr = lane & 15;          // fragment row/col index

  for (int k0 = 0; k0 < K; k0 += 32) {
    __syncthreads();
    gload16(Ag0 + k0, AsW0);
    gload16(Ag1 + k0, AsW1);
    gload16(Bg0 + k0, BsW0);
    gload16(Bg1 + k0, BsW1);
    __syncthreads();
    bf16x8 af[4], bf[4];
#pragma unroll
    for (int i = 0; i < 4; ++i) {
      af[i] = *(const bf16x8*)&As[(wr + i * 16 + fr) * 32 + kq];
      bf[i] = *(const bf16x8*)&Bs[(wc + i * 16 + fr) * 32 + kq];
    }
#pragma unroll
    for (int i = 0; i < 4; ++i)
#pragma unroll
      for (int j = 0; j < 4; ++j)
        acc[i][j] = __builtin_amdgcn_mfma_f32_16x16x32_bf16(af[i], bf[j],
                                                            acc[i][j], 0, 0, 0);
  }

  const int fq = (lane >> 4) * 4;
#pragma unroll
  for (int j = 0; j < 4; ++j) {
    const int n = n0 + wc + j * 16 + fr;
    const float bb = bias[n];
#pragma unroll
    for (int i = 0; i < 4; ++i) {
      const int mbase = m0 + wr + i * 16 + fq;
#pragma unroll
      for (int r = 0; r < 4; ++r) {
        const int m = mbase + r;
        if (m < M) {
          const float v = acc[i][j][r] + bb;
          if (MODE == 0) ((float*)C)[(size_t)m * N + n] = v;
          else if (MODE == 1) ((float*)C)[(size_t)m * N + n] += v;
          else ((u16*)C)[(size_t)m * N + n] = bf16r(gelu_f(v));
        }
      }
    }
  }
}

// ---------------- probe attention + top-k, one block per batch ----------------
__global__ __launch_bounds__(256) void probe_topk(const float* __restrict__ qkv,
                                                  const int* __restrict__ kpptr,
                                                  int* __restrict__ topk) {
  __shared__ float qrow[64];
  __shared__ float s[NTOK];
  __shared__ float accsc[NTOK];
  __shared__ float red[4];
  const int b = blockIdx.x, tid = threadIdx.x;
  const size_t row0 = (size_t)b * NTOK * QKVD;
  for (int k = tid; k < NTOK; k += 256) accsc[k] = 0.f;
  for (int h = 0; h < HEADS; ++h) {
    __syncthreads();
    if (tid < 64) qrow[tid] = qkv[row0 + h * HEADD + tid];
    __syncthreads();
    for (int k = tid; k < NTOK; k += 256) {
      const float* kr = qkv + row0 + (size_t)k * QKVD + DMODEL + h * HEADD;
      float dot = 0.f;
#pragma unroll 8
      for (int d = 0; d < 64; ++d) dot = fmaf(qrow[d], kr[d], dot);
      s[k] = dot * 0.125f;
    }
    __syncthreads();
    float mx = -1e30f;
    for (int k = tid; k < NTOK; k += 256) mx = fmaxf(mx, s[k]);
    mx = blk_red_max(mx, red);
    float sm = 0.f;
    for (int k = tid; k < NTOK; k += 256) sm += expf(s[k] - mx);
    sm = blk_red_sum(sm, red);
    float inv = 1.f / sm;
    for (int k = tid; k < NTOK; k += 256) accsc[k] += expf(s[k] - mx) * inv;
  }
  __syncthreads();
  if (tid == 0) {
    int kpn = kpptr[0];
    if (kpn < 0) kpn = 0;
    if (kpn > 8) kpn = 8;
    for (int j = 0; j < kpn; ++j) {
      float best = -1e30f;
      int bi = 1;
      for (int k = 1; k < NTOK; ++k)
        if (accsc[k] > best) { best = accsc[k]; bi = k; }
      topk[b * 8 + j] = bi;
      accsc[bi] = -2e30f;
    }
    for (int j = kpn; j < 8; ++j) topk[b * 8 + j] = -1;
  }
}

// ---------------- fused attention, one block per (b, h); bf16 output -----------
__global__ __launch_bounds__(256) void attn_fused(
    const float* __restrict__ qkv, const float* __restrict__ prompt_k,
    const float* __restrict__ prompt_v, const float* __restrict__ pk,
    const float* __restrict__ pv, const int* __restrict__ topk,
    const int* __restrict__ kpptr, u16* __restrict__ outp) {
  __shared__ float kmod_t[64 * NTOK];  // [d][k]
  __shared__ float pbuf[16][NTOK];
  __shared__ float qbuf[4][64];
  __shared__ float selb[NTOK];
  const int bh = blockIdx.x;
  const int b = bh / HEADS, h = bh % HEADS;
  const int tid = threadIdx.x, w = tid >> 6, lane = tid & 63;
  int kpn = kpptr[0];
  if (kpn < 0) kpn = 0;
  if (kpn > 8) kpn = 8;
  for (int k = tid; k < NTOK; k += 256) {
    float sl = 0.f;
    for (int j = 0; j < kpn; ++j)
      if (topk[b * 8 + j] == k) sl = 1.f;
    selb[k] = sl;
  }
  __syncthreads();
  const size_t row0 = (size_t)b * NTOK * QKVD;
  const float* kbase = qkv + row0 + DMODEL + h * HEADD;
  for (int idx = tid; idx < NTOK * 64; idx += 256) {
    int kk = idx >> 6, d = idx & 63;
    float v = kbase[(size_t)kk * QKVD + d];
    if (kk == 0) v += prompt_k[h * HEADD + d];
    v += selb[kk] * pk[h * HEADD + d];
    kmod_t[d * NTOK + kk] = v;
  }
  __syncthreads();
  const float pvp = prompt_v[h * HEADD + lane];
  const float pvv = pv[h * HEADD + lane];
  const float* qbase = qkv + row0 + h * HEADD;
  const float* vbase = qkv + row0 + 2 * DMODEL + h * HEADD;
  u16* obase = outp + (size_t)b * NTOK * DMODEL + h * HEADD;

  for (int r0 = 0; r0 < NTOK; r0 += 16) {
#pragma unroll
    for (int rr = 0; rr < 4; ++rr) {
      int q = r0 + w * 4 + rr;
      if (q >= NTOK) continue;
      qbuf[w][lane] = qbase[(size_t)q * QKVD + lane];
      float sc[4];
#pragma unroll
      for (int j = 0; j < 4; ++j) {
        int k = lane + j * 64;
        if (k < NTOK) {
          float dot = 0.f;
#pragma unroll 8
          for (int d = 0; d < 64; ++d)
            dot = fmaf(qbuf[w][d], kmod_t[d * NTOK + k], dot);
          sc[j] = dot * 0.125f;
        } else {
          sc[j] = -1e30f;
        }
      }
      float mx = fmaxf(fmaxf(sc[0], sc[1]), fmaxf(sc[2], sc[3]));
#pragma unroll
      for (int o = 32; o; o >>= 1) mx = fmaxf(mx, __shfl_xor(mx, o));
      float pr[4];
      float sm = 0.f;
#pragma unroll
      for (int j = 0; j < 4; ++j) {
        pr[j] = __expf(sc[j] - mx);
        if (lane + j * 64 >= NTOK) pr[j] = 0.f;
        sm += pr[j];
      }
#pragma unroll
      for (int o = 32; o; o >>= 1) sm += __shfl_xor(sm, o);
      float inv = 1.f / sm;
#pragma unroll
      for (int j = 0; j < 4; ++j) {
        int k = lane + j * 64;
        if (k < NTOK) pbuf[w * 4 + rr][k] = pr[j] * inv;
      }
    }
    float a0 = 0.f, a1 = 0.f, a2 = 0.f, a3 = 0.f;
    for (int k = 0; k < NTOK; ++k) {
      float vv = vbase[(size_t)k * QKVD + lane];
      if (k == 0) vv += pvp;
      vv += selb[k] * pvv;
      a0 = fmaf(pbuf[w * 4 + 0][k], vv, a0);
      a1 = fmaf(pbuf[w * 4 + 1][k], vv, a1);
      a2 = fmaf(pbuf[w * 4 + 2][k], vv, a2);
      a3 = fmaf(pbuf[w * 4 + 3][k], vv, a3);
    }
    int q0 = r0 + w * 4;
    if (q0 + 0 < NTOK) obase[(size_t)(q0 + 0) * DMODEL + lane] = bf16r(a0);
    if (q0 + 1 < NTOK) obase[(size_t)(q0 + 1) * DMODEL + lane] = bf16r(a1);
    if (q0 + 2 < NTOK) obase[(size_t)(q0 + 2) * DMODEL + lane] = bf16r(a2);
    if (q0 + 3 < NTOK) obase[(size_t)(q0 + 3) * DMODEL + lane] = bf16r(a3);
  }
}

// ---------------- host ----------------
extern "C" void kernel_launch(void* const* d_in, const int* in_sizes, int n_in,
                              void* d_out, int out_size, void* d_ws, size_t ws_size,
                              hipStream_t stream) {
  const float* x = (const float*)d_in[0];
  const float* patch_w = (const float*)d_in[1];
  const float* patch_b = (const float*)d_in[2];
  const float* cls_tok = (const float*)d_in[3];
  const float* pos_emb = (const float*)d_in[4];
  const float* ln1_w = (const float*)d_in[5];
  const float* ln1_b = (const float*)d_in[6];
  const float* qkv_w = (const float*)d_in[7];
  const float* qkv_b = (const float*)d_in[8];
  const float* proj_w = (const float*)d_in[9];
  const float* proj_b = (const float*)d_in[10];
  const float* pk_par = (const float*)d_in[11];
  const float* pv_par = (const float*)d_in[12];
  const float* pr_k = (const float*)d_in[13];
  const float* pr_v = (const float*)d_in[14];
  const float* ln2_w = (const float*)d_in[15];
  const float* ln2_b = (const float*)d_in[16];
  const float* fc1_w = (const float*)d_in[17];
  const float* fc1_b = (const float*)d_in[18];
  const float* fc2_w = (const float*)d_in[19];
  const float* fc2_b = (const float*)d_in[20];
  const float* norm_w = (const float*)d_in[21];
  const float* norm_b = (const float*)d_in[22];
  const int* kp = (const int*)d_in[23];

  float* tokens = (float*)d_ws;
  float* bufh = tokens + (size_t)MTOK * DMODEL;
  float* bufbig = bufh + (size_t)MTOK * DMODEL;
  u16* wbuf = (u16*)(bufbig + (size_t)MTOK * MLPD);
  u16* im2colb = wbuf + WTOTAL;
  int* topk = (int*)(im2colb + (size_t)MPAT * DMODEL);

  const int mt = (MTOK + 127) / 128;  // 50

  // patch embedding: convert patch_w -> im2col(bf16) -> MFMA GEMM -> assemble
  convert_bf16<<<(DMODEL * DMODEL / 4 + 255) / 256, 256, 0, stream>>>(
      patch_w, wbuf, DMODEL * DMODEL);
  im2col<<<(MPAT * DMODEL + 255) / 256, 256, 0, stream>>>(x, im2colb);
  gemm_bf16<0><<<dim3(MPAT / 128, DMODEL / 128), 256, 0, stream>>>(
      im2colb, wbuf, patch_b, bufh, MPAT, DMODEL, DMODEL);
  assemble<<<(MTOK * DMODEL + 255) / 256, 256, 0, stream>>>(bufh, cls_tok,
                                                            pos_emb, tokens);

  for (int l = 0; l < DEPTH; ++l) {
    convert_layer_w<<<(WTOTAL / 4 + 255) / 256, 256, 0, stream>>>(
        qkv_w + (size_t)l * QKVD * DMODEL, proj_w + (size_t)l * DMODEL * DMODEL,
        fc1_w + (size_t)l * MLPD * DMODEL, fc2_w + (size_t)l * DMODEL * MLPD,
        wbuf);
    layernorm<true><<<MTOK, 256, 0, stream>>>(tokens, ln1_w + l * DMODEL,
                                              ln1_b + l * DMODEL, bufh);
    gemm_bf16<0><<<dim3(mt, QKVD / 128), 256, 0, stream>>>(
        (const u16*)bufh, wbuf + OFF_QKV, qkv_b + l * QKVD, bufbig,
        MTOK, QKVD, DMODEL);
    probe_topk<<<BATCH, 256, 0, stream>>>(bufbig, kp, topk);
    attn_fused<<<BATCH * HEADS, 256, 0, stream>>>(
        bufbig, pr_k + l * HEADS * HEADD, pr_v + l * HEADS * HEADD,
        pk_par + l * HEADS * HEADD, pv_par + l * HEADS * HEADD, topk, kp,
        (u16*)bufh);
    gemm_bf16<1><<<dim3(mt, DMODEL / 128), 256, 0, stream>>>(
        (const u16*)bufh, wbuf + OFF_PROJ, proj_b + l * DMODEL, tokens,
        MTOK, DMODEL, DMODEL);
    layernorm<true><<<MTOK, 256, 0, stream>>>(tokens, ln2_w + l * DMODEL,
                                              ln2_b + l * DMODEL, bufh);
    gemm_bf16<2><<<dim3(mt, MLPD / 128), 256, 0, stream>>>(
        (const u16*)bufh, wbuf + OFF_FC1, fc1_b + l * MLPD, bufbig,
        MTOK, MLPD, DMODEL);
    gemm_bf16<1><<<dim3(mt, DMODEL / 128), 256, 0, stream>>>(
        (const u16*)bufbig, wbuf + OFF_FC2, fc2_b + l * DMODEL, tokens,
        MTOK, DMODEL, MLPD);
  }
  layernorm<false><<<MTOK, 256, 0, stream>>>(tokens, norm_w, norm_b, d_out);
}

// Round 3
// 4818.464 us; speedup vs baseline: 4.2247x; 1.6600x over previous
//
#include <hip/hip_runtime.h>
#include <math.h>

#define DMODEL 768
#define DEPTH 12
#define HEADS 12
#define HEADD 64
#define NTOK 197
#define BATCH 32
#define NPATCH 196
#define MTOK (BATCH * NTOK)    // 6304
#define MPAT (BATCH * NPATCH)  // 6272
#define QKVD 2304
#define MLPD 3072

typedef unsigned short u16;
typedef __attribute__((ext_vector_type(8))) short bf16x8;
typedef __attribute__((ext_vector_type(4))) float f32x4;

// weight staging offsets (elements) inside per-layer bf16 buffer
#define OFF_QKV 0
#define OFF_PROJ (QKVD * DMODEL)
#define OFF_FC1 (OFF_PROJ + DMODEL * DMODEL)
#define OFF_FC2 (OFF_FC1 + MLPD * DMODEL)
#define WTOTAL (OFF_FC2 + DMODEL * MLPD)

__device__ __forceinline__ u16 bf16r(float x) {
  union { float f; unsigned u; } c; c.f = x;
  unsigned u = c.u + 0x7FFF + ((c.u >> 16) & 1);
  return (u16)(u >> 16);
}
__device__ __forceinline__ float gelu_f(float x) {
  return 0.5f * x * (1.f + erff(x * 0.70710678118654752440f));
}
__device__ __forceinline__ void gload16(const void* g, void* l) {
  __builtin_amdgcn_global_load_lds(
      (const __attribute__((address_space(1))) void*)g,
      (__attribute__((address_space(3))) void*)l, 16, 0, 0);
}

// ---------------- block-wide reductions (256 threads = 4 waves) ----------------
__device__ __forceinline__ float blk_red_sum(float v, float* red) {
#pragma unroll
  for (int o = 32; o; o >>= 1) v += __shfl_xor(v, o);
  __syncthreads();
  if ((threadIdx.x & 63) == 0) red[threadIdx.x >> 6] = v;
  __syncthreads();
  return red[0] + red[1] + red[2] + red[3];
}
__device__ __forceinline__ float blk_red_max(float v, float* red) {
#pragma unroll
  for (int o = 32; o; o >>= 1) v = fmaxf(v, __shfl_xor(v, o));
  __syncthreads();
  if ((threadIdx.x & 63) == 0) red[threadIdx.x >> 6] = v;
  __syncthreads();
  return fmaxf(fmaxf(red[0], red[1]), fmaxf(red[2], red[3]));
}

// ---------------- f32 -> bf16 conversions ----------------
__global__ __launch_bounds__(256) void convert_bf16(const float* __restrict__ in,
                                                    u16* __restrict__ out, int n) {
  int i = (blockIdx.x * 256 + threadIdx.x) * 4;
  if (i >= n) return;
  float4 v = *(const float4*)(in + i);
  ushort4 o;
  o.x = bf16r(v.x); o.y = bf16r(v.y); o.z = bf16r(v.z); o.w = bf16r(v.w);
  *(ushort4*)(out + i) = o;
}

__global__ __launch_bounds__(256) void convert_layer_w(
    const float* __restrict__ qkv_w, const float* __restrict__ proj_w,
    const float* __restrict__ fc1_w, const float* __restrict__ fc2_w,
    u16* __restrict__ wbuf) {
  int i = (blockIdx.x * 256 + threadIdx.x) * 4;
  if (i >= WTOTAL) return;
  const float* s;
  if (i < OFF_PROJ) s = qkv_w + i;
  else if (i < OFF_FC1) s = proj_w + (i - OFF_PROJ);
  else if (i < OFF_FC2) s = fc1_w + (i - OFF_FC1);
  else s = fc2_w + (i - OFF_FC2);
  float4 v = *(const float4*)s;
  ushort4 o;
  o.x = bf16r(v.x); o.y = bf16r(v.y); o.z = bf16r(v.z); o.w = bf16r(v.w);
  *(ushort4*)(wbuf + i) = o;
}

// ---------------- im2col for patch embedding (bf16 out) ----------------
__global__ __launch_bounds__(256) void im2col(const float* __restrict__ x,
                                              u16* __restrict__ col) {
  int idx = blockIdx.x * 256 + threadIdx.x;
  if (idx >= MPAT * DMODEL) return;
  int kk = idx % DMODEL;
  int m = idx / DMODEL;
  int bb = m / NPATCH, p = m % NPATCH;
  int ph = p / 14, pw = p % 14;
  int ch = kk >> 8, rem = kk & 255;
  int i = rem >> 4, j = rem & 15;
  col[idx] = bf16r(x[(((size_t)bb * 3 + ch) * 224 + ph * 16 + i) * 224 + pw * 16 + j]);
}

// ---------------- token assembly ----------------
__global__ __launch_bounds__(256) void assemble(const float* __restrict__ pat,
                                                const float* __restrict__ cls,
                                                const float* __restrict__ pos,
                                                float* __restrict__ tokens) {
  int idx = blockIdx.x * 256 + threadIdx.x;
  if (idx >= MTOK * DMODEL) return;
  int c = idx % DMODEL;
  int t = idx / DMODEL;
  int bb = t / NTOK, n = t % NTOK;
  float v;
  if (n == 0) v = cls[c];
  else v = pat[((size_t)bb * NPATCH + (n - 1)) * DMODEL + c];
  tokens[idx] = v + pos[n * DMODEL + c];
}

// ---------------- LayerNorm ----------------
template <bool BF16OUT>
__global__ __launch_bounds__(256) void layernorm(const float* __restrict__ in,
                                                 const float* __restrict__ w,
                                                 const float* __restrict__ b,
                                                 void* __restrict__ outp) {
  __shared__ float red[4];
  const int t = blockIdx.x, tid = threadIdx.x;
  const float* r = in + (size_t)t * DMODEL;
  float x0 = r[tid], x1 = r[tid + 256], x2 = r[tid + 512];
  float mu = blk_red_sum(x0 + x1 + x2, red) * (1.f / 768.f);
  float d0 = x0 - mu, d1 = x1 - mu, d2 = x2 - mu;
  float var = blk_red_sum(d0 * d0 + d1 * d1 + d2 * d2, red) * (1.f / 768.f);
  float is = rsqrtf(var + 1e-6f);
  float v0 = d0 * is * w[tid] + b[tid];
  float v1 = d1 * is * w[tid + 256] + b[tid + 256];
  float v2 = d2 * is * w[tid + 512] + b[tid + 512];
  if (BF16OUT) {
    u16* o = (u16*)outp + (size_t)t * DMODEL;
    o[tid] = bf16r(v0); o[tid + 256] = bf16r(v1); o[tid + 512] = bf16r(v2);
  } else {
    float* o = (float*)outp + (size_t)t * DMODEL;
    o[tid] = v0; o[tid + 256] = v1; o[tid + 512] = v2;
  }
}

// ---------------- bf16 MFMA NT GEMM (unchanged from round 2) ----------------
template <int MODE>
__global__ __launch_bounds__(256) void gemm_bf16(const u16* __restrict__ A,
                                                 const u16* __restrict__ B,
                                                 const float* __restrict__ bias,
                                                 void* __restrict__ C,
                                                 int M, int N, int K) {
  __shared__ u16 As[128 * 32];
  __shared__ u16 Bs[128 * 32];
  const int tid = threadIdx.x;
  const int w = tid >> 6, lane = tid & 63;
  const int m0 = blockIdx.x * 128, n0 = blockIdx.y * 128;
  const int wr = (w >> 1) * 64, wc = (w & 1) * 64;
  f32x4 acc[4][4] = {};

  const int srow = tid >> 2;
  const int scol = (tid & 3) * 8;
  int ar0 = m0 + srow;       if (ar0 >= M) ar0 = M - 1;
  int ar1 = m0 + 64 + srow;  if (ar1 >= M) ar1 = M - 1;
  const u16* Ag0 = A + (size_t)ar0 * K + scol;
  const u16* Ag1 = A + (size_t)ar1 * K + scol;
  const u16* Bg0 = B + (size_t)(n0 + srow) * K + scol;
  const u16* Bg1 = B + (size_t)(n0 + 64 + srow) * K + scol;
  u16* AsW0 = As + w * 512;
  u16* AsW1 = As + 2048 + w * 512;
  u16* BsW0 = Bs + w * 512;
  u16* BsW1 = Bs + 2048 + w * 512;

  const int kq = (lane >> 4) * 8;
  const int fr = lane & 15;

  for (int k0 = 0; k0 < K; k0 += 32) {
    __syncthreads();
    gload16(Ag0 + k0, AsW0);
    gload16(Ag1 + k0, AsW1);
    gload16(Bg0 + k0, BsW0);
    gload16(Bg1 + k0, BsW1);
    __syncthreads();
    bf16x8 af[4], bf[4];
#pragma unroll
    for (int i = 0; i < 4; ++i) {
      af[i] = *(const bf16x8*)&As[(wr + i * 16 + fr) * 32 + kq];
      bf[i] = *(const bf16x8*)&Bs[(wc + i * 16 + fr) * 32 + kq];
    }
#pragma unroll
    for (int i = 0; i < 4; ++i)
#pragma unroll
      for (int j = 0; j < 4; ++j)
        acc[i][j] = __builtin_amdgcn_mfma_f32_16x16x32_bf16(af[i], bf[j],
                                                            acc[i][j], 0, 0, 0);
  }

  const int fq = (lane >> 4) * 4;
#pragma unroll
  for (int j = 0; j < 4; ++j) {
    const int n = n0 + wc + j * 16 + fr;
    const float bb = bias[n];
#pragma unroll
    for (int i = 0; i < 4; ++i) {
      const int mbase = m0 + wr + i * 16 + fq;
#pragma unroll
      for (int r = 0; r < 4; ++r) {
        const int m = mbase + r;
        if (m < M) {
          const float v = acc[i][j][r] + bb;
          if (MODE == 0) ((float*)C)[(size_t)m * N + n] = v;
          else if (MODE == 1) ((float*)C)[(size_t)m * N + n] += v;
          else ((u16*)C)[(size_t)m * N + n] = bf16r(gelu_f(v));
        }
      }
    }
  }
}

// ---------------- probe attention + top-k, one block per batch ----------------
__global__ __launch_bounds__(256) void probe_topk(const float* __restrict__ qkv,
                                                  const int* __restrict__ kpptr,
                                                  int* __restrict__ topk) {
  __shared__ float qrow[64];
  __shared__ float s[NTOK];
  __shared__ float accsc[NTOK];
  __shared__ float red[4];
  const int b = blockIdx.x, tid = threadIdx.x;
  const size_t row0 = (size_t)b * NTOK * QKVD;
  for (int k = tid; k < NTOK; k += 256) accsc[k] = 0.f;
  const int sub = tid & 3;
  for (int h = 0; h < HEADS; ++h) {
    __syncthreads();
    if (tid < 64) qrow[tid] = qkv[row0 + h * HEADD + tid];
    __syncthreads();
    for (int k = tid >> 2; k < NTOK; k += 64) {
      const float* kr = qkv + row0 + (size_t)k * QKVD + DMODEL + h * HEADD + sub * 16;
      float dot = 0.f;
#pragma unroll
      for (int c = 0; c < 4; ++c) {
        float4 kv = *(const float4*)(kr + c * 4);
        dot = fmaf(qrow[sub * 16 + c * 4 + 0], kv.x, dot);
        dot = fmaf(qrow[sub * 16 + c * 4 + 1], kv.y, dot);
        dot = fmaf(qrow[sub * 16 + c * 4 + 2], kv.z, dot);
        dot = fmaf(qrow[sub * 16 + c * 4 + 3], kv.w, dot);
      }
      dot += __shfl_xor(dot, 1);
      dot += __shfl_xor(dot, 2);
      if (sub == 0) s[k] = dot * 0.125f;
    }
    __syncthreads();
    float mx = -1e30f;
    for (int k = tid; k < NTOK; k += 256) mx = fmaxf(mx, s[k]);
    mx = blk_red_max(mx, red);
    float sm = 0.f;
    for (int k = tid; k < NTOK; k += 256) sm += expf(s[k] - mx);
    sm = blk_red_sum(sm, red);
    float inv = 1.f / sm;
    for (int k = tid; k < NTOK; k += 256) accsc[k] += expf(s[k] - mx) * inv;
  }
  __syncthreads();
  if (tid == 0) {
    int kpn = kpptr[0];
    if (kpn < 0) kpn = 0;
    if (kpn > 8) kpn = 8;
    for (int j = 0; j < kpn; ++j) {
      float best = -1e30f;
      int bi = 1;
      for (int k = 1; k < NTOK; ++k)
        if (accsc[k] > best) { best = accsc[k]; bi = k; }
      topk[b * 8 + j] = bi;
      accsc[bi] = -2e30f;
    }
    for (int j = kpn; j < 8; ++j) topk[b * 8 + j] = -1;
  }
}

// ---------------- MFMA attention: one block per (b,h), 8 waves ----------------
// Tokens padded to 208 for S (13 j-tiles of 16), 224 for PV (7 k-chunks of 32).
// Ks: [208][64] bf16, row pitch 128B, swizzle byte^=((tok&7)<<4)
// Vs: V^T [64][256] bf16, row pitch 512B, swizzle byte^=((d&7)<<4)
// Ps: per wave [16][256] bf16, pitch 512B, swizzle byte^=((row&7)<<4)
__device__ __forceinline__ bf16x8 pack8(float4 a, float4 b) {
  bf16x8 r;
  r[0] = (short)bf16r(a.x); r[1] = (short)bf16r(a.y);
  r[2] = (short)bf16r(a.z); r[3] = (short)bf16r(a.w);
  r[4] = (short)bf16r(b.x); r[5] = (short)bf16r(b.y);
  r[6] = (short)bf16r(b.z); r[7] = (short)bf16r(b.w);
  return r;
}

__global__ __launch_bounds__(512, 1) void attn_mfma(
    const float* __restrict__ qkv, const float* __restrict__ prompt_k,
    const float* __restrict__ prompt_v, const float* __restrict__ pk,
    const float* __restrict__ pv, const int* __restrict__ topk,
    const int* __restrict__ kpptr, u16* __restrict__ outp) {
  __shared__ u16 Ks[208 * 64];      // 26624 B
  __shared__ u16 Vs[64 * 256];      // 32768 B
  __shared__ u16 Ps[8][16 * 256];   // 65536 B
  __shared__ float selb[NTOK];
  const int bh = blockIdx.x;
  const int b = bh / HEADS, h = bh % HEADS;
  const int tid = threadIdx.x, w = tid >> 6, lane = tid & 63;
  const int fr = lane & 15, lq = lane >> 4;  // fragment row/col, k-quarter

  int kpn = kpptr[0];
  if (kpn < 0) kpn = 0;
  if (kpn > 8) kpn = 8;
  for (int k = tid; k < NTOK; k += 512) {
    float sl = 0.f;
    for (int j = 0; j < kpn; ++j)
      if (topk[b * 8 + j] == k) sl = 1.f;
    selb[k] = sl;
  }
  __syncthreads();

  const size_t row0 = (size_t)b * NTOK * QKVD;
  const float* kg = qkv + row0 + DMODEL + h * HEADD;
  const float* vg = qkv + row0 + 2 * DMODEL + h * HEADD;
  // stage K_mod -> Ks (swizzled)
  for (int idx = tid; idx < 208 * 64; idx += 512) {
    int tok = idx >> 6, d = idx & 63;
    float v = 0.f;
    if (tok < NTOK) {
      v = kg[(size_t)tok * QKVD + d] + selb[tok] * pk[h * HEADD + d];
      if (tok == 0) v += prompt_k[h * HEADD + d];
    }
    int off = (tok * 128 + d * 2) ^ ((tok & 7) << 4);
    *(u16*)((char*)Ks + off) = bf16r(v);
  }
  // stage V_mod^T -> Vs (swizzled)
  for (int idx = tid; idx < 224 * 64; idx += 512) {
    int tok = idx >> 6, d = idx & 63;
    float v = 0.f;
    if (tok < NTOK) {
      v = vg[(size_t)tok * QKVD + d] + selb[tok] * pv[h * HEADD + d];
      if (tok == 0) v += prompt_v[h * HEADD + d];
    }
    int off = (d * 512 + tok * 2) ^ ((d & 7) << 4);
    *(u16*)((char*)Vs + off) = bf16r(v);
  }
  __syncthreads();

  u16* Pw = Ps[w];
  u16* ob = outp + (size_t)b * NTOK * DMODEL + h * HEADD;

#pragma unroll
  for (int pass = 0; pass < 2; ++pass) {
    const int qt = pass * 8 + w;
    const bool active = (qt < 14);
    if (active) {
      // Q A-fragments straight from global (f32 -> bf16)
      int qrow = qt * 16 + fr;
      if (qrow > NTOK - 1) qrow = NTOK - 1;
      const float* qp = qkv + row0 + (size_t)qrow * QKVD + h * HEADD + lq * 8;
      bf16x8 aq0 = pack8(*(const float4*)qp, *(const float4*)(qp + 4));
      bf16x8 aq1 = pack8(*(const float4*)(qp + 32), *(const float4*)(qp + 36));
      // S = Q K^T (13 fragments in registers)
      f32x4 sa[13];
#pragma unroll
      for (int j = 0; j < 13; ++j) {
        int tok = j * 16 + fr;
        int o0 = (tok * 128 + lq * 16) ^ ((tok & 7) << 4);
        int o1 = (tok * 128 + 64 + lq * 16) ^ ((tok & 7) << 4);
        bf16x8 bk0 = *(const bf16x8*)((const char*)Ks + o0);
        bf16x8 bk1 = *(const bf16x8*)((const char*)Ks + o1);
        f32x4 z = {0.f, 0.f, 0.f, 0.f};
        z = __builtin_amdgcn_mfma_f32_16x16x32_bf16(aq0, bk0, z, 0, 0, 0);
        sa[j] = __builtin_amdgcn_mfma_f32_16x16x32_bf16(aq1, bk1, z, 0, 0, 0);
      }
      // in-register softmax over 13 fragments x 16 lanes
      const bool v12 = (fr < 5);  // tile 12: tokens 192+fr valid iff fr<5
      float m4[4] = {-1e30f, -1e30f, -1e30f, -1e30f};
#pragma unroll
      for (int j = 0; j < 13; ++j) {
        if (j == 12 && !v12) continue;
#pragma unroll
        for (int r = 0; r < 4; ++r) m4[r] = fmaxf(m4[r], sa[j][r] * 0.125f);
      }
#pragma unroll
      for (int o = 8; o; o >>= 1)
#pragma unroll
        for (int r = 0; r < 4; ++r) m4[r] = fmaxf(m4[r], __shfl_xor(m4[r], o));
      float s4[4] = {0.f, 0.f, 0.f, 0.f};
#pragma unroll
      for (int j = 0; j < 13; ++j) {
        const bool valid = (j < 12) || v12;
#pragma unroll
        for (int r = 0; r < 4; ++r) {
          float p = valid ? __expf(sa[j][r] * 0.125f - m4[r]) : 0.f;
          sa[j][r] = p;
          s4[r] += p;
        }
      }
#pragma unroll
      for (int o = 8; o; o >>= 1)
#pragma unroll
        for (int r = 0; r < 4; ++r) s4[r] += __shfl_xor(s4[r], o);
      float inv[4];
#pragma unroll
      for (int r = 0; r < 4; ++r) inv[r] = 1.f / s4[r];
      // write P (bf16, swizzled); zero cols 208..223 for the last PV chunk
#pragma unroll
      for (int r = 0; r < 4; ++r) {
        int row = lq * 4 + r;
        int rbase = row * 512, sw = (row & 7) << 4;
#pragma unroll
        for (int j = 0; j < 13; ++j) {
          int off = (rbase + (j * 16 + fr) * 2) ^ sw;
          *(u16*)((char*)Pw + off) = bf16r(sa[j][r] * inv[r]);
        }
        int offz = (rbase + (208 + fr) * 2) ^ sw;
        *(u16*)((char*)Pw + offz) = 0;
      }
    }
    __syncthreads();  // P visible (all threads reach this)
    if (active) {
      // O = P V : 4 d-tiles, 7 k-chunks of 32
      f32x4 oa[4] = {};
#pragma unroll
      for (int kc = 0; kc < 7; ++kc) {
        int po = (fr * 512 + (kc * 32 + lq * 8) * 2) ^ ((fr & 7) << 4);
        bf16x8 pa = *(const bf16x8*)((const char*)Pw + po);
#pragma unroll
        for (int dt = 0; dt < 4; ++dt) {
          int d = dt * 16 + fr;
          int vo = (d * 512 + (kc * 32 + lq * 8) * 2) ^ ((d & 7) << 4);
          bf16x8 vb = *(const bf16x8*)((const char*)Vs + vo);
          oa[dt] = __builtin_amdgcn_mfma_f32_16x16x32_bf16(pa, vb, oa[dt], 0, 0, 0);
        }
      }
      // store O rows (q = qt*16 + lq*4 + r, d-col = dt*16 + fr)
#pragma unroll
      for (int r = 0; r < 4; ++r) {
        int q = qt * 16 + lq * 4 + r;
        if (q < NTOK) {
          u16* orow = ob + (size_t)q * DMODEL;
#pragma unroll
          for (int dt = 0; dt < 4; ++dt) orow[dt * 16 + fr] = bf16r(oa[dt][r]);
        }
      }
    }
    __syncthreads();  // protect Ps rewrite in next pass
  }
}

// ---------------- host ----------------
extern "C" void kernel_launch(void* const* d_in, const int* in_sizes, int n_in,
                              void* d_out, int out_size, void* d_ws, size_t ws_size,
                              hipStream_t stream) {
  const float* x = (const float*)d_in[0];
  const float* patch_w = (const float*)d_in[1];
  const float* patch_b = (const float*)d_in[2];
  const float* cls_tok = (const float*)d_in[3];
  const float* pos_emb = (const float*)d_in[4];
  const float* ln1_w = (const float*)d_in[5];
  const float* ln1_b = (const float*)d_in[6];
  const float* qkv_w = (const float*)d_in[7];
  const float* qkv_b = (const float*)d_in[8];
  const float* proj_w = (const float*)d_in[9];
  const float* proj_b = (const float*)d_in[10];
  const float* pk_par = (const float*)d_in[11];
  const float* pv_par = (const float*)d_in[12];
  const float* pr_k = (const float*)d_in[13];
  const float* pr_v = (const float*)d_in[14];
  const float* ln2_w = (const float*)d_in[15];
  const float* ln2_b = (const float*)d_in[16];
  const float* fc1_w = (const float*)d_in[17];
  const float* fc1_b = (const float*)d_in[18];
  const float* fc2_w = (const float*)d_in[19];
  const float* fc2_b = (const float*)d_in[20];
  const float* norm_w = (const float*)d_in[21];
  const float* norm_b = (const float*)d_in[22];
  const int* kp = (const int*)d_in[23];

  float* tokens = (float*)d_ws;
  float* bufh = tokens + (size_t)MTOK * DMODEL;
  float* bufbig = bufh + (size_t)MTOK * DMODEL;
  u16* wbuf = (u16*)(bufbig + (size_t)MTOK * MLPD);
  u16* im2colb = wbuf + WTOTAL;
  int* topk = (int*)(im2colb + (size_t)MPAT * DMODEL);

  const int mt = (MTOK + 127) / 128;

  convert_bf16<<<(DMODEL * DMODEL / 4 + 255) / 256, 256, 0, stream>>>(
      patch_w, wbuf, DMODEL * DMODEL);
  im2col<<<(MPAT * DMODEL + 255) / 256, 256, 0, stream>>>(x, im2colb);
  gemm_bf16<0><<<dim3(MPAT / 128, DMODEL / 128), 256, 0, stream>>>(
      im2colb, wbuf, patch_b, bufh, MPAT, DMODEL, DMODEL);
  assemble<<<(MTOK * DMODEL + 255) / 256, 256, 0, stream>>>(bufh, cls_tok,
                                                            pos_emb, tokens);

  for (int l = 0; l < DEPTH; ++l) {
    convert_layer_w<<<(WTOTAL / 4 + 255) / 256, 256, 0, stream>>>(
        qkv_w + (size_t)l * QKVD * DMODEL, proj_w + (size_t)l * DMODEL * DMODEL,
        fc1_w + (size_t)l * MLPD * DMODEL, fc2_w + (size_t)l * DMODEL * MLPD,
        wbuf);
    layernorm<true><<<MTOK, 256, 0, stream>>>(tokens, ln1_w + l * DMODEL,
                                              ln1_b + l * DMODEL, bufh);
    gemm_bf16<0><<<dim3(mt, QKVD / 128), 256, 0, stream>>>(
        (const u16*)bufh, wbuf + OFF_QKV, qkv_b + l * QKVD, bufbig,
        MTOK, QKVD, DMODEL);
    probe_topk<<<BATCH, 256, 0, stream>>>(bufbig, kp, topk);
    attn_mfma<<<BATCH * HEADS, 512, 0, stream>>>(
        bufbig, pr_k + l * HEADS * HEADD, pr_v + l * HEADS * HEADD,
        pk_par + l * HEADS * HEADD, pv_par + l * HEADS * HEADD, topk, kp,
        (u16*)bufh);
    gemm_bf16<1><<<dim3(mt, DMODEL / 128), 256, 0, stream>>>(
        (const u16*)bufh, wbuf + OFF_PROJ, proj_b + l * DMODEL, tokens,
        MTOK, DMODEL, DMODEL);
    layernorm<true><<<MTOK, 256, 0, stream>>>(tokens, ln2_w + l * DMODEL,
                                              ln2_b + l * DMODEL, bufh);
    gemm_bf16<2><<<dim3(mt, MLPD / 128), 256, 0, stream>>>(
        (const u16*)bufh, wbuf + OFF_FC1, fc1_b + l * MLPD, bufbig,
        MTOK, MLPD, DMODEL);
    gemm_bf16<1><<<dim3(mt, DMODEL / 128), 256, 0, stream>>>(
        (const u16*)bufbig, wbuf + OFF_FC2, fc2_b + l * DMODEL, tokens,
        MTOK, DMODEL, MLPD);
  }
  layernorm<false><<<MTOK, 256, 0, stream>>>(tokens, norm_w, norm_b, d_out);
}

// Round 4
// 4503.654 us; speedup vs baseline: 4.5200x; 1.0699x over previous
//
#include <hip/hip_runtime.h>
#include <math.h>

#define DMODEL 768
#define DEPTH 12
#define HEADS 12
#define HEADD 64
#define NTOK 197
#define BATCH 32
#define NPATCH 196
#define MTOK (BATCH * NTOK)    // 6304
#define MPAT (BATCH * NPATCH)  // 6272
#define QKVD 2304
#define MLPD 3072

typedef unsigned short u16;
typedef __attribute__((ext_vector_type(8))) short bf16x8;
typedef __attribute__((ext_vector_type(4))) float f32x4;

#define OFF_QKV 0
#define OFF_PROJ (QKVD * DMODEL)
#define OFF_FC1 (OFF_PROJ + DMODEL * DMODEL)
#define OFF_FC2 (OFF_FC1 + MLPD * DMODEL)
#define WTOTAL (OFF_FC2 + DMODEL * MLPD)

__device__ __forceinline__ u16 bf16r(float x) {
  union { float f; unsigned u; } c; c.f = x;
  unsigned u = c.u + 0x7FFF + ((c.u >> 16) & 1);
  return (u16)(u >> 16);
}
__device__ __forceinline__ float gelu_f(float x) {
  return 0.5f * x * (1.f + erff(x * 0.70710678118654752440f));
}
__device__ __forceinline__ void gload16(const void* g, void* l) {
  __builtin_amdgcn_global_load_lds(
      (const __attribute__((address_space(1))) void*)g,
      (__attribute__((address_space(3))) void*)l, 16, 0, 0);
}

// ---------------- block-wide reductions ----------------
__device__ __forceinline__ float blk_red_sum(float v, float* red) {
#pragma unroll
  for (int o = 32; o; o >>= 1) v += __shfl_xor(v, o);
  __syncthreads();
  if ((threadIdx.x & 63) == 0) red[threadIdx.x >> 6] = v;
  __syncthreads();
  return red[0] + red[1] + red[2] + red[3];
}
__device__ __forceinline__ float blk_red_max(float v, float* red) {
#pragma unroll
  for (int o = 32; o; o >>= 1) v = fmaxf(v, __shfl_xor(v, o));
  __syncthreads();
  if ((threadIdx.x & 63) == 0) red[threadIdx.x >> 6] = v;
  __syncthreads();
  return fmaxf(fmaxf(red[0], red[1]), fmaxf(red[2], red[3]));
}

// ---------------- f32 -> bf16 conversions ----------------
__global__ __launch_bounds__(256) void convert_bf16(const float* __restrict__ in,
                                                    u16* __restrict__ out, int n) {
  int i = (blockIdx.x * 256 + threadIdx.x) * 4;
  if (i >= n) return;
  float4 v = *(const float4*)(in + i);
  ushort4 o;
  o.x = bf16r(v.x); o.y = bf16r(v.y); o.z = bf16r(v.z); o.w = bf16r(v.w);
  *(ushort4*)(out + i) = o;
}

__global__ __launch_bounds__(256) void convert_layer_w(
    const float* __restrict__ qkv_w, const float* __restrict__ proj_w,
    const float* __restrict__ fc1_w, const float* __restrict__ fc2_w,
    u16* __restrict__ wbuf) {
  int i = (blockIdx.x * 256 + threadIdx.x) * 4;
  if (i >= WTOTAL) return;
  const float* s;
  if (i < OFF_PROJ) s = qkv_w + i;
  else if (i < OFF_FC1) s = proj_w + (i - OFF_PROJ);
  else if (i < OFF_FC2) s = fc1_w + (i - OFF_FC1);
  else s = fc2_w + (i - OFF_FC2);
  float4 v = *(const float4*)s;
  ushort4 o;
  o.x = bf16r(v.x); o.y = bf16r(v.y); o.z = bf16r(v.z); o.w = bf16r(v.w);
  *(ushort4*)(wbuf + i) = o;
}

// ---------------- im2col (bf16 out) ----------------
__global__ __launch_bounds__(256) void im2col(const float* __restrict__ x,
                                              u16* __restrict__ col) {
  int idx = blockIdx.x * 256 + threadIdx.x;
  if (idx >= MPAT * DMODEL) return;
  int kk = idx % DMODEL;
  int m = idx / DMODEL;
  int bb = m / NPATCH, p = m % NPATCH;
  int ph = p / 14, pw = p % 14;
  int ch = kk >> 8, rem = kk & 255;
  int i = rem >> 4, j = rem & 15;
  col[idx] = bf16r(x[(((size_t)bb * 3 + ch) * 224 + ph * 16 + i) * 224 + pw * 16 + j]);
}

// ---------------- token assembly ----------------
__global__ __launch_bounds__(256) void assemble(const float* __restrict__ pat,
                                                const float* __restrict__ cls,
                                                const float* __restrict__ pos,
                                                float* __restrict__ tokens) {
  int idx = blockIdx.x * 256 + threadIdx.x;
  if (idx >= MTOK * DMODEL) return;
  int c = idx % DMODEL;
  int t = idx / DMODEL;
  int bb = t / NTOK, n = t % NTOK;
  float v;
  if (n == 0) v = cls[c];
  else v = pat[((size_t)bb * NPATCH + (n - 1)) * DMODEL + c];
  tokens[idx] = v + pos[n * DMODEL + c];
}

// ---------------- LayerNorm ----------------
template <bool BF16OUT>
__global__ __launch_bounds__(256) void layernorm(const float* __restrict__ in,
                                                 const float* __restrict__ w,
                                                 const float* __restrict__ b,
                                                 void* __restrict__ outp) {
  __shared__ float red[4];
  const int t = blockIdx.x, tid = threadIdx.x;
  const float* r = in + (size_t)t * DMODEL;
  float x0 = r[tid], x1 = r[tid + 256], x2 = r[tid + 512];
  float mu = blk_red_sum(x0 + x1 + x2, red) * (1.f / 768.f);
  float d0 = x0 - mu, d1 = x1 - mu, d2 = x2 - mu;
  float var = blk_red_sum(d0 * d0 + d1 * d1 + d2 * d2, red) * (1.f / 768.f);
  float is = rsqrtf(var + 1e-6f);
  float v0 = d0 * is * w[tid] + b[tid];
  float v1 = d1 * is * w[tid + 256] + b[tid + 256];
  float v2 = d2 * is * w[tid + 512] + b[tid + 512];
  if (BF16OUT) {
    u16* o = (u16*)outp + (size_t)t * DMODEL;
    o[tid] = bf16r(v0); o[tid + 256] = bf16r(v1); o[tid + 512] = bf16r(v2);
  } else {
    float* o = (float*)outp + (size_t)t * DMODEL;
    o[tid] = v0; o[tid + 256] = v1; o[tid + 512] = v2;
  }
}

// ------- bf16 MFMA NT GEMM, 2-phase double-buffered prefetch -------
// Tile 128 x TN, BK=32, 4 waves. TN in {64,128}.
// MODE 0: C(f32)=acc+bias ; 1: C(f32)+=acc+bias ; 2: C(bf16)=gelu(acc+bias)
template <int MODE, int TN>
__global__ __launch_bounds__(256) void gemm2(const u16* __restrict__ A,
                                             const u16* __restrict__ B,
                                             const float* __restrict__ bias,
                                             void* __restrict__ C,
                                             int M, int N, int K) {
  __shared__ u16 As[2][128 * 32];
  __shared__ u16 Bs[2][TN * 32];
  const int tid = threadIdx.x;
  const int w = tid >> 6, lane = tid & 63;

  // bijective XCD-chunked swizzle (m204): round-robin xcd -> contiguous chunk
  const int nwg = gridDim.x * gridDim.y;
  int lin = blockIdx.y * gridDim.x + blockIdx.x;
  {
    int q = nwg >> 3, r = nwg & 7;
    int xcd = lin & 7, idx = lin >> 3;
    lin = (xcd < r ? xcd * (q + 1) : r * (q + 1) + (xcd - r) * q) + idx;
  }
  const int mt = gridDim.x;
  const int m0 = (lin % mt) * 128, n0 = (lin / mt) * TN;

  const int wr = (w >> 1) * 64, wc = (w & 1) * (TN / 2);
  constexpr int NJ = TN / 32;
  f32x4 acc[4][NJ] = {};

  // staging map: thread t -> row t/4 (0..63), k-bytes [(t&3)*16, +16)
  const int srow = tid >> 2;
  const int scol = (tid & 3) * 8;
  int ar0 = m0 + srow;       if (ar0 >= M) ar0 = M - 1;
  int ar1 = m0 + 64 + srow;  if (ar1 >= M) ar1 = M - 1;
  const u16* Ag0 = A + (size_t)ar0 * K + scol;
  const u16* Ag1 = A + (size_t)ar1 * K + scol;
  const u16* Bg0 = B + (size_t)(n0 + srow) * K + scol;
  const u16* Bg1 = B + (size_t)(n0 + (TN == 128 ? 64 : 0) + srow) * K + scol;

  auto STAGE = [&](int buf, int kk) {
    gload16(Ag0 + kk, &As[buf][w * 512]);
    gload16(Ag1 + kk, &As[buf][2048 + w * 512]);
    gload16(Bg0 + kk, &Bs[buf][w * 512]);
    if (TN == 128) gload16(Bg1 + kk, &Bs[buf][2048 + w * 512]);
  };

  const int kq = (lane >> 4) * 8;
  const int fr = lane & 15;

  STAGE(0, 0);
  __syncthreads();  // drains vmcnt -> buf0 ready
  int cur = 0;
  for (int k0 = 0; k0 < K; k0 += 32) {
    if (k0 + 32 < K) STAGE(cur ^ 1, k0 + 32);  // async prefetch next tile
    bf16x8 af[4], bfr[NJ];
#pragma unroll
    for (int i = 0; i < 4; ++i)
      af[i] = *(const bf16x8*)&As[cur][(wr + i * 16 + fr) * 32 + kq];
#pragma unroll
    for (int j = 0; j < NJ; ++j)
      bfr[j] = *(const bf16x8*)&Bs[cur][(wc + j * 16 + fr) * 32 + kq];
#pragma unroll
    for (int i = 0; i < 4; ++i)
#pragma unroll
      for (int j = 0; j < NJ; ++j)
        acc[i][j] = __builtin_amdgcn_mfma_f32_16x16x32_bf16(af[i], bfr[j],
                                                            acc[i][j], 0, 0, 0);
    __syncthreads();  // drains vmcnt(0): prefetched buf ready; cur buf reusable
    cur ^= 1;
  }

  const int fq = (lane >> 4) * 4;
#pragma unroll
  for (int j = 0; j < NJ; ++j) {
    const int n = n0 + wc + j * 16 + fr;
    const float bb = bias[n];
#pragma unroll
    for (int i = 0; i < 4; ++i) {
      const int mbase = m0 + wr + i * 16 + fq;
#pragma unroll
      for (int r = 0; r < 4; ++r) {
        const int m = mbase + r;
        if (m < M) {
          const float v = acc[i][j][r] + bb;
          if (MODE == 0) ((float*)C)[(size_t)m * N + n] = v;
          else if (MODE == 1) ((float*)C)[(size_t)m * N + n] += v;
          else ((u16*)C)[(size_t)m * N + n] = bf16r(gelu_f(v));
        }
      }
    }
  }
}

// ---------------- probe attention + top-k ----------------
__global__ __launch_bounds__(256) void probe_topk(const float* __restrict__ qkv,
                                                  const int* __restrict__ kpptr,
                                                  int* __restrict__ topk) {
  __shared__ float qrow[64];
  __shared__ float s[NTOK];
  __shared__ float accsc[NTOK];
  __shared__ float red[4];
  const int b = blockIdx.x, tid = threadIdx.x;
  const size_t row0 = (size_t)b * NTOK * QKVD;
  for (int k = tid; k < NTOK; k += 256) accsc[k] = 0.f;
  const int sub = tid & 3;
  for (int h = 0; h < HEADS; ++h) {
    __syncthreads();
    if (tid < 64) qrow[tid] = qkv[row0 + h * HEADD + tid];
    __syncthreads();
    for (int k = tid >> 2; k < NTOK; k += 64) {
      const float* kr = qkv + row0 + (size_t)k * QKVD + DMODEL + h * HEADD + sub * 16;
      float dot = 0.f;
#pragma unroll
      for (int c = 0; c < 4; ++c) {
        float4 kv = *(const float4*)(kr + c * 4);
        dot = fmaf(qrow[sub * 16 + c * 4 + 0], kv.x, dot);
        dot = fmaf(qrow[sub * 16 + c * 4 + 1], kv.y, dot);
        dot = fmaf(qrow[sub * 16 + c * 4 + 2], kv.z, dot);
        dot = fmaf(qrow[sub * 16 + c * 4 + 3], kv.w, dot);
      }
      dot += __shfl_xor(dot, 1);
      dot += __shfl_xor(dot, 2);
      if (sub == 0) s[k] = dot * 0.125f;
    }
    __syncthreads();
    float mx = -1e30f;
    for (int k = tid; k < NTOK; k += 256) mx = fmaxf(mx, s[k]);
    mx = blk_red_max(mx, red);
    float sm = 0.f;
    for (int k = tid; k < NTOK; k += 256) sm += expf(s[k] - mx);
    sm = blk_red_sum(sm, red);
    float inv = 1.f / sm;
    for (int k = tid; k < NTOK; k += 256) accsc[k] += expf(s[k] - mx) * inv;
  }
  __syncthreads();
  if (tid == 0) {
    int kpn = kpptr[0];
    if (kpn < 0) kpn = 0;
    if (kpn > 8) kpn = 8;
    for (int j = 0; j < kpn; ++j) {
      float best = -1e30f;
      int bi = 1;
      for (int k = 1; k < NTOK; ++k)
        if (accsc[k] > best) { best = accsc[k]; bi = k; }
      topk[b * 8 + j] = bi;
      accsc[bi] = -2e30f;
    }
    for (int j = kpn; j < 8; ++j) topk[b * 8 + j] = -1;
  }
}

// ---------------- MFMA attention (unchanged from round 3) ----------------
__device__ __forceinline__ bf16x8 pack8(float4 a, float4 b) {
  bf16x8 r;
  r[0] = (short)bf16r(a.x); r[1] = (short)bf16r(a.y);
  r[2] = (short)bf16r(a.z); r[3] = (short)bf16r(a.w);
  r[4] = (short)bf16r(b.x); r[5] = (short)bf16r(b.y);
  r[6] = (short)bf16r(b.z); r[7] = (short)bf16r(b.w);
  return r;
}

__global__ __launch_bounds__(512, 1) void attn_mfma(
    const float* __restrict__ qkv, const float* __restrict__ prompt_k,
    const float* __restrict__ prompt_v, const float* __restrict__ pk,
    const float* __restrict__ pv, const int* __restrict__ topk,
    const int* __restrict__ kpptr, u16* __restrict__ outp) {
  __shared__ u16 Ks[208 * 64];
  __shared__ u16 Vs[64 * 256];
  __shared__ u16 Ps[8][16 * 256];
  __shared__ float selb[NTOK];
  const int bh = blockIdx.x;
  const int b = bh / HEADS, h = bh % HEADS;
  const int tid = threadIdx.x, w = tid >> 6, lane = tid & 63;
  const int fr = lane & 15, lq = lane >> 4;

  int kpn = kpptr[0];
  if (kpn < 0) kpn = 0;
  if (kpn > 8) kpn = 8;
  for (int k = tid; k < NTOK; k += 512) {
    float sl = 0.f;
    for (int j = 0; j < kpn; ++j)
      if (topk[b * 8 + j] == k) sl = 1.f;
    selb[k] = sl;
  }
  __syncthreads();

  const size_t row0 = (size_t)b * NTOK * QKVD;
  const float* kg = qkv + row0 + DMODEL + h * HEADD;
  const float* vg = qkv + row0 + 2 * DMODEL + h * HEADD;
  for (int idx = tid; idx < 208 * 64; idx += 512) {
    int tok = idx >> 6, d = idx & 63;
    float v = 0.f;
    if (tok < NTOK) {
      v = kg[(size_t)tok * QKVD + d] + selb[tok] * pk[h * HEADD + d];
      if (tok == 0) v += prompt_k[h * HEADD + d];
    }
    int off = (tok * 128 + d * 2) ^ ((tok & 7) << 4);
    *(u16*)((char*)Ks + off) = bf16r(v);
  }
  for (int idx = tid; idx < 224 * 64; idx += 512) {
    int tok = idx >> 6, d = idx & 63;
    float v = 0.f;
    if (tok < NTOK) {
      v = vg[(size_t)tok * QKVD + d] + selb[tok] * pv[h * HEADD + d];
      if (tok == 0) v += prompt_v[h * HEADD + d];
    }
    int off = (d * 512 + tok * 2) ^ ((d & 7) << 4);
    *(u16*)((char*)Vs + off) = bf16r(v);
  }
  __syncthreads();

  u16* Pw = Ps[w];
  u16* ob = outp + (size_t)b * NTOK * DMODEL + h * HEADD;

#pragma unroll
  for (int pass = 0; pass < 2; ++pass) {
    const int qt = pass * 8 + w;
    const bool active = (qt < 14);
    if (active) {
      int qrow = qt * 16 + fr;
      if (qrow > NTOK - 1) qrow = NTOK - 1;
      const float* qp = qkv + row0 + (size_t)qrow * QKVD + h * HEADD + lq * 8;
      bf16x8 aq0 = pack8(*(const float4*)qp, *(const float4*)(qp + 4));
      bf16x8 aq1 = pack8(*(const float4*)(qp + 32), *(const float4*)(qp + 36));
      f32x4 sa[13];
#pragma unroll
      for (int j = 0; j < 13; ++j) {
        int tok = j * 16 + fr;
        int o0 = (tok * 128 + lq * 16) ^ ((tok & 7) << 4);
        int o1 = (tok * 128 + 64 + lq * 16) ^ ((tok & 7) << 4);
        bf16x8 bk0 = *(const bf16x8*)((const char*)Ks + o0);
        bf16x8 bk1 = *(const bf16x8*)((const char*)Ks + o1);
        f32x4 z = {0.f, 0.f, 0.f, 0.f};
        z = __builtin_amdgcn_mfma_f32_16x16x32_bf16(aq0, bk0, z, 0, 0, 0);
        sa[j] = __builtin_amdgcn_mfma_f32_16x16x32_bf16(aq1, bk1, z, 0, 0, 0);
      }
      const bool v12 = (fr < 5);
      float m4[4] = {-1e30f, -1e30f, -1e30f, -1e30f};
#pragma unroll
      for (int j = 0; j < 13; ++j) {
        if (j == 12 && !v12) continue;
#pragma unroll
        for (int r = 0; r < 4; ++r) m4[r] = fmaxf(m4[r], sa[j][r] * 0.125f);
      }
#pragma unroll
      for (int o = 8; o; o >>= 1)
#pragma unroll
        for (int r = 0; r < 4; ++r) m4[r] = fmaxf(m4[r], __shfl_xor(m4[r], o));
      float s4[4] = {0.f, 0.f, 0.f, 0.f};
#pragma unroll
      for (int j = 0; j < 13; ++j) {
        const bool valid = (j < 12) || v12;
#pragma unroll
        for (int r = 0; r < 4; ++r) {
          float p = valid ? __expf(sa[j][r] * 0.125f - m4[r]) : 0.f;
          sa[j][r] = p;
          s4[r] += p;
        }
      }
#pragma unroll
      for (int o = 8; o; o >>= 1)
#pragma unroll
        for (int r = 0; r < 4; ++r) s4[r] += __shfl_xor(s4[r], o);
      float inv[4];
#pragma unroll
      for (int r = 0; r < 4; ++r) inv[r] = 1.f / s4[r];
#pragma unroll
      for (int r = 0; r < 4; ++r) {
        int row = lq * 4 + r;
        int rbase = row * 512, sw = (row & 7) << 4;
#pragma unroll
        for (int j = 0; j < 13; ++j) {
          int off = (rbase + (j * 16 + fr) * 2) ^ sw;
          *(u16*)((char*)Pw + off) = bf16r(sa[j][r] * inv[r]);
        }
        int offz = (rbase + (208 + fr) * 2) ^ sw;
        *(u16*)((char*)Pw + offz) = 0;
      }
    }
    __syncthreads();
    if (active) {
      f32x4 oa[4] = {};
#pragma unroll
      for (int kc = 0; kc < 7; ++kc) {
        int po = (fr * 512 + (kc * 32 + lq * 8) * 2) ^ ((fr & 7) << 4);
        bf16x8 pa = *(const bf16x8*)((const char*)Pw + po);
#pragma unroll
        for (int dt = 0; dt < 4; ++dt) {
          int d = dt * 16 + fr;
          int vo = (d * 512 + (kc * 32 + lq * 8) * 2) ^ ((d & 7) << 4);
          bf16x8 vb = *(const bf16x8*)((const char*)Vs + vo);
          oa[dt] = __builtin_amdgcn_mfma_f32_16x16x32_bf16(pa, vb, oa[dt], 0, 0, 0);
        }
      }
#pragma unroll
      for (int r = 0; r < 4; ++r) {
        int q = qt * 16 + lq * 4 + r;
        if (q < NTOK) {
          u16* orow = ob + (size_t)q * DMODEL;
#pragma unroll
          for (int dt = 0; dt < 4; ++dt) orow[dt * 16 + fr] = bf16r(oa[dt][r]);
        }
      }
    }
    __syncthreads();
  }
}

// ---------------- host ----------------
extern "C" void kernel_launch(void* const* d_in, const int* in_sizes, int n_in,
                              void* d_out, int out_size, void* d_ws, size_t ws_size,
                              hipStream_t stream) {
  const float* x = (const float*)d_in[0];
  const float* patch_w = (const float*)d_in[1];
  const float* patch_b = (const float*)d_in[2];
  const float* cls_tok = (const float*)d_in[3];
  const float* pos_emb = (const float*)d_in[4];
  const float* ln1_w = (const float*)d_in[5];
  const float* ln1_b = (const float*)d_in[6];
  const float* qkv_w = (const float*)d_in[7];
  const float* qkv_b = (const float*)d_in[8];
  const float* proj_w = (const float*)d_in[9];
  const float* proj_b = (const float*)d_in[10];
  const float* pk_par = (const float*)d_in[11];
  const float* pv_par = (const float*)d_in[12];
  const float* pr_k = (const float*)d_in[13];
  const float* pr_v = (const float*)d_in[14];
  const float* ln2_w = (const float*)d_in[15];
  const float* ln2_b = (const float*)d_in[16];
  const float* fc1_w = (const float*)d_in[17];
  const float* fc1_b = (const float*)d_in[18];
  const float* fc2_w = (const float*)d_in[19];
  const float* fc2_b = (const float*)d_in[20];
  const float* norm_w = (const float*)d_in[21];
  const float* norm_b = (const float*)d_in[22];
  const int* kp = (const int*)d_in[23];

  float* tokens = (float*)d_ws;
  float* bufh = tokens + (size_t)MTOK * DMODEL;
  float* bufbig = bufh + (size_t)MTOK * DMODEL;
  u16* wbuf = (u16*)(bufbig + (size_t)MTOK * MLPD);
  u16* im2colb = wbuf + WTOTAL;
  int* topk = (int*)(im2colb + (size_t)MPAT * DMODEL);

  const int mt = (MTOK + 127) / 128;   // 50
  const int mtp = (MPAT + 127) / 128;  // 49

  convert_bf16<<<(DMODEL * DMODEL / 4 + 255) / 256, 256, 0, stream>>>(
      patch_w, wbuf, DMODEL * DMODEL);
  im2col<<<(MPAT * DMODEL + 255) / 256, 256, 0, stream>>>(x, im2colb);
  gemm2<0, 64><<<dim3(mtp, DMODEL / 64), 256, 0, stream>>>(
      im2colb, wbuf, patch_b, bufh, MPAT, DMODEL, DMODEL);
  assemble<<<(MTOK * DMODEL + 255) / 256, 256, 0, stream>>>(bufh, cls_tok,
                                                            pos_emb, tokens);

  for (int l = 0; l < DEPTH; ++l) {
    convert_layer_w<<<(WTOTAL / 4 + 255) / 256, 256, 0, stream>>>(
        qkv_w + (size_t)l * QKVD * DMODEL, proj_w + (size_t)l * DMODEL * DMODEL,
        fc1_w + (size_t)l * MLPD * DMODEL, fc2_w + (size_t)l * DMODEL * MLPD,
        wbuf);
    layernorm<true><<<MTOK, 256, 0, stream>>>(tokens, ln1_w + l * DMODEL,
                                              ln1_b + l * DMODEL, bufh);
    gemm2<0, 128><<<dim3(mt, QKVD / 128), 256, 0, stream>>>(
        (const u16*)bufh, wbuf + OFF_QKV, qkv_b + l * QKVD, bufbig,
        MTOK, QKVD, DMODEL);
    probe_topk<<<BATCH, 256, 0, stream>>>(bufbig, kp, topk);
    attn_mfma<<<BATCH * HEADS, 512, 0, stream>>>(
        bufbig, pr_k + l * HEADS * HEADD, pr_v + l * HEADS * HEADD,
        pk_par + l * HEADS * HEADD, pv_par + l * HEADS * HEADD, topk, kp,
        (u16*)bufh);
    gemm2<1, 64><<<dim3(mt, DMODEL / 64), 256, 0, stream>>>(
        (const u16*)bufh, wbuf + OFF_PROJ, proj_b + l * DMODEL, tokens,
        MTOK, DMODEL, DMODEL);
    layernorm<true><<<MTOK, 256, 0, stream>>>(tokens, ln2_w + l * DMODEL,
                                              ln2_b + l * DMODEL, bufh);
    gemm2<2, 128><<<dim3(mt, MLPD / 128), 256, 0, stream>>>(
        (const u16*)bufh, wbuf + OFF_FC1, fc1_b + l * MLPD, bufbig,
        MTOK, MLPD, DMODEL);
    gemm2<1, 64><<<dim3(mt, DMODEL / 64), 256, 0, stream>>>(
        (const u16*)bufbig, wbuf + OFF_FC2, fc2_b + l * DMODEL, tokens,
        MTOK, DMODEL, MLPD);
  }
  layernorm<false><<<MTOK, 256, 0, stream>>>(tokens, norm_w, norm_b, d_out);
}

// Round 5
// 4156.799 us; speedup vs baseline: 4.8972x; 1.0834x over previous
//
#include <hip/hip_runtime.h>
#include <math.h>

#define DMODEL 768
#define DEPTH 12
#define HEADS 12
#define HEADD 64
#define NTOK 197
#define BATCH 32
#define NPATCH 196
#define MTOK (BATCH * NTOK)    // 6304
#define MPAT (BATCH * NPATCH)  // 6272
#define QKVD 2304
#define MLPD 3072

typedef unsigned short u16;
typedef __attribute__((ext_vector_type(8))) short bf16x8;
typedef __attribute__((ext_vector_type(4))) float f32x4;

#define OFF_QKV 0
#define OFF_PROJ (QKVD * DMODEL)
#define OFF_FC1 (OFF_PROJ + DMODEL * DMODEL)
#define OFF_FC2 (OFF_FC1 + MLPD * DMODEL)
#define WTOTAL (OFF_FC2 + DMODEL * MLPD)

__device__ __forceinline__ u16 bf16r(float x) {
  union { float f; unsigned u; } c; c.f = x;
  unsigned u = c.u + 0x7FFF + ((c.u >> 16) & 1);
  return (u16)(u >> 16);
}
__device__ __forceinline__ float gelu_f(float x) {
  return 0.5f * x * (1.f + erff(x * 0.70710678118654752440f));
}
__device__ __forceinline__ void gload16(const void* g, void* l) {
  __builtin_amdgcn_global_load_lds(
      (const __attribute__((address_space(1))) void*)g,
      (__attribute__((address_space(3))) void*)l, 16, 0, 0);
}

// ---------------- block-wide reductions ----------------
__device__ __forceinline__ float blk_red_sum(float v, float* red) {
#pragma unroll
  for (int o = 32; o; o >>= 1) v += __shfl_xor(v, o);
  __syncthreads();
  if ((threadIdx.x & 63) == 0) red[threadIdx.x >> 6] = v;
  __syncthreads();
  return red[0] + red[1] + red[2] + red[3];
}
__device__ __forceinline__ float blk_red_max(float v, float* red) {
#pragma unroll
  for (int o = 32; o; o >>= 1) v = fmaxf(v, __shfl_xor(v, o));
  __syncthreads();
  if ((threadIdx.x & 63) == 0) red[threadIdx.x >> 6] = v;
  __syncthreads();
  return fmaxf(fmaxf(red[0], red[1]), fmaxf(red[2], red[3]));
}

// ---------------- f32 -> bf16 conversions ----------------
__global__ __launch_bounds__(256) void convert_bf16(const float* __restrict__ in,
                                                    u16* __restrict__ out, int n) {
  int i = (blockIdx.x * 256 + threadIdx.x) * 4;
  if (i >= n) return;
  float4 v = *(const float4*)(in + i);
  ushort4 o;
  o.x = bf16r(v.x); o.y = bf16r(v.y); o.z = bf16r(v.z); o.w = bf16r(v.w);
  *(ushort4*)(out + i) = o;
}

__global__ __launch_bounds__(256) void convert_layer_w(
    const float* __restrict__ qkv_w, const float* __restrict__ proj_w,
    const float* __restrict__ fc1_w, const float* __restrict__ fc2_w,
    u16* __restrict__ wbuf) {
  int i = (blockIdx.x * 256 + threadIdx.x) * 4;
  if (i >= WTOTAL) return;
  const float* s;
  if (i < OFF_PROJ) s = qkv_w + i;
  else if (i < OFF_FC1) s = proj_w + (i - OFF_PROJ);
  else if (i < OFF_FC2) s = fc1_w + (i - OFF_FC1);
  else s = fc2_w + (i - OFF_FC2);
  float4 v = *(const float4*)s;
  ushort4 o;
  o.x = bf16r(v.x); o.y = bf16r(v.y); o.z = bf16r(v.z); o.w = bf16r(v.w);
  *(ushort4*)(wbuf + i) = o;
}

// ---------------- im2col (bf16 out) ----------------
__global__ __launch_bounds__(256) void im2col(const float* __restrict__ x,
                                              u16* __restrict__ col) {
  int idx = blockIdx.x * 256 + threadIdx.x;
  if (idx >= MPAT * DMODEL) return;
  int kk = idx % DMODEL;
  int m = idx / DMODEL;
  int bb = m / NPATCH, p = m % NPATCH;
  int ph = p / 14, pw = p % 14;
  int ch = kk >> 8, rem = kk & 255;
  int i = rem >> 4, j = rem & 15;
  col[idx] = bf16r(x[(((size_t)bb * 3 + ch) * 224 + ph * 16 + i) * 224 + pw * 16 + j]);
}

// ---------------- token assembly ----------------
__global__ __launch_bounds__(256) void assemble(const float* __restrict__ pat,
                                                const float* __restrict__ cls,
                                                const float* __restrict__ pos,
                                                float* __restrict__ tokens) {
  int idx = blockIdx.x * 256 + threadIdx.x;
  if (idx >= MTOK * DMODEL) return;
  int c = idx % DMODEL;
  int t = idx / DMODEL;
  int bb = t / NTOK, n = t % NTOK;
  float v;
  if (n == 0) v = cls[c];
  else v = pat[((size_t)bb * NPATCH + (n - 1)) * DMODEL + c];
  tokens[idx] = v + pos[n * DMODEL + c];
}

// ---------------- LayerNorm ----------------
template <bool BF16OUT>
__global__ __launch_bounds__(256) void layernorm(const float* __restrict__ in,
                                                 const float* __restrict__ w,
                                                 const float* __restrict__ b,
                                                 void* __restrict__ outp) {
  __shared__ float red[4];
  const int t = blockIdx.x, tid = threadIdx.x;
  const float* r = in + (size_t)t * DMODEL;
  float x0 = r[tid], x1 = r[tid + 256], x2 = r[tid + 512];
  float mu = blk_red_sum(x0 + x1 + x2, red) * (1.f / 768.f);
  float d0 = x0 - mu, d1 = x1 - mu, d2 = x2 - mu;
  float var = blk_red_sum(d0 * d0 + d1 * d1 + d2 * d2, red) * (1.f / 768.f);
  float is = rsqrtf(var + 1e-6f);
  float v0 = d0 * is * w[tid] + b[tid];
  float v1 = d1 * is * w[tid + 256] + b[tid + 256];
  float v2 = d2 * is * w[tid + 512] + b[tid + 512];
  if (BF16OUT) {
    u16* o = (u16*)outp + (size_t)t * DMODEL;
    o[tid] = bf16r(v0); o[tid + 256] = bf16r(v1); o[tid + 512] = bf16r(v2);
  } else {
    float* o = (float*)outp + (size_t)t * DMODEL;
    o[tid] = v0; o[tid + 256] = v1; o[tid + 512] = v2;
  }
}

// ------- bf16 MFMA NT GEMM: 3-buffer, 2-ahead prefetch, counted vmcnt -------
// Tile 128 x TN, BK=32, 4 waves. Read-side chunk swizzle (kcol^row&3, 16B
// granule) with pre-swizzled GLOBAL source (LDS dest stays linear for
// global_load_lds — rule #21).
// MODE 0: C(f32)=acc+bias ; 1: C(f32)+=acc+bias ; 2: C(bf16)=gelu(acc+bias)
template <int MODE, int TN>
__global__ __launch_bounds__(256) void gemm3(const u16* __restrict__ A,
                                             const u16* __restrict__ B,
                                             const float* __restrict__ bias,
                                             void* __restrict__ C,
                                             int M, int N, int K) {
  constexpr int NJ = TN / 32;
  constexpr int LPT = (TN == 128) ? 4 : 3;  // gload16 per wave per tile
  __shared__ u16 As[3][128 * 32];
  __shared__ u16 Bs[3][TN * 32];
  const int tid = threadIdx.x;
  const int w = tid >> 6, lane = tid & 63;

  // bijective XCD-chunked swizzle (m204)
  const int nwg = gridDim.x * gridDim.y;
  int lin = blockIdx.y * gridDim.x + blockIdx.x;
  {
    int q = nwg >> 3, r = nwg & 7;
    int xcd = lin & 7, idx = lin >> 3;
    lin = (xcd < r ? xcd * (q + 1) : r * (q + 1) + (xcd - r) * q) + idx;
  }
  const int mt = gridDim.x;
  const int m0 = (lin % mt) * 128, n0 = (lin / mt) * TN;

  const int wr = (w >> 1) * 64, wc = (w & 1) * (TN / 2);
  f32x4 acc[4][NJ] = {};

  // staging map: thread t -> row t/4 within 64-row half, chunk (t&3)^(row&3)
  const int srow = tid >> 2;
  const int scol = ((tid & 3) ^ (srow & 3)) * 8;  // pre-swizzled global chunk
  int ar0 = m0 + srow;       if (ar0 >= M) ar0 = M - 1;
  int ar1 = m0 + 64 + srow;  if (ar1 >= M) ar1 = M - 1;
  const u16* Ag0 = A + (size_t)ar0 * K + scol;
  const u16* Ag1 = A + (size_t)ar1 * K + scol;
  const u16* Bg0 = B + (size_t)(n0 + srow) * K + scol;
  const u16* Bg1 = B + (size_t)(n0 + (TN == 128 ? 64 : 0) + srow) * K + scol;

  auto STAGE = [&](int buf, int kk) {
    gload16(Ag0 + kk, &As[buf][w * 512]);
    gload16(Ag1 + kk, &As[buf][2048 + w * 512]);
    gload16(Bg0 + kk, &Bs[buf][w * 512]);
    if (TN == 128) gload16(Bg1 + kk, &Bs[buf][2048 + w * 512]);
  };

  const int fr = lane & 15, lq = lane >> 4;
  const int kq = (lq ^ (fr & 3)) * 8;  // swizzled chunk on the read side

  const int nt = K >> 5;
  STAGE(0, 0);
  STAGE(1, 32);
  asm volatile("s_waitcnt vmcnt(%0)" ::"n"(LPT) : "memory");
  __builtin_amdgcn_s_barrier();
  __builtin_amdgcn_sched_barrier(0);

  for (int t = 0; t < nt; ++t) {
    const int cur = t % 3;
    bf16x8 af[4], bfr[NJ];
#pragma unroll
    for (int i = 0; i < 4; ++i)
      af[i] = *(const bf16x8*)&As[cur][(wr + i * 16 + fr) * 32 + kq];
#pragma unroll
    for (int j = 0; j < NJ; ++j)
      bfr[j] = *(const bf16x8*)&Bs[cur][(wc + j * 16 + fr) * 32 + kq];
    const bool more = (t + 2 < nt);
    if (more) STAGE((t + 2) % 3, (t + 2) * 32);
#pragma unroll
    for (int i = 0; i < 4; ++i)
#pragma unroll
      for (int j = 0; j < NJ; ++j)
        acc[i][j] = __builtin_amdgcn_mfma_f32_16x16x32_bf16(af[i], bfr[j],
                                                            acc[i][j], 0, 0, 0);
    if (more)
      asm volatile("s_waitcnt vmcnt(%0)" ::"n"(LPT) : "memory");
    else
      asm volatile("s_waitcnt vmcnt(0)" ::: "memory");
    __builtin_amdgcn_s_barrier();
    __builtin_amdgcn_sched_barrier(0);
  }

  const int fq = lq * 4;
#pragma unroll
  for (int j = 0; j < NJ; ++j) {
    const int n = n0 + wc + j * 16 + fr;
    const float bb = bias[n];
#pragma unroll
    for (int i = 0; i < 4; ++i) {
      const int mbase = m0 + wr + i * 16 + fq;
#pragma unroll
      for (int r = 0; r < 4; ++r) {
        const int m = mbase + r;
        if (m < M) {
          const float v = acc[i][j][r] + bb;
          if (MODE == 0) ((float*)C)[(size_t)m * N + n] = v;
          else if (MODE == 1) ((float*)C)[(size_t)m * N + n] += v;
          else ((u16*)C)[(size_t)m * N + n] = bf16r(gelu_f(v));
        }
      }
    }
  }
}

// ---------------- probe scores: one block per (b,h) ----------------
__global__ __launch_bounds__(256) void probe_scores(const float* __restrict__ qkv,
                                                    float* __restrict__ probs) {
  __shared__ float qrow[64];
  __shared__ float s[NTOK];
  __shared__ float red[4];
  const int bh = blockIdx.x;
  const int b = bh / HEADS, h = bh % HEADS;
  const int tid = threadIdx.x;
  const size_t row0 = (size_t)b * NTOK * QKVD;
  if (tid < 64) qrow[tid] = qkv[row0 + h * HEADD + tid];
  __syncthreads();
  const int sub = tid & 3;
  for (int k = tid >> 2; k < NTOK; k += 64) {
    const float* kr = qkv + row0 + (size_t)k * QKVD + DMODEL + h * HEADD + sub * 16;
    float dot = 0.f;
#pragma unroll
    for (int c = 0; c < 4; ++c) {
      float4 kv = *(const float4*)(kr + c * 4);
      dot = fmaf(qrow[sub * 16 + c * 4 + 0], kv.x, dot);
      dot = fmaf(qrow[sub * 16 + c * 4 + 1], kv.y, dot);
      dot = fmaf(qrow[sub * 16 + c * 4 + 2], kv.z, dot);
      dot = fmaf(qrow[sub * 16 + c * 4 + 3], kv.w, dot);
    }
    dot += __shfl_xor(dot, 1);
    dot += __shfl_xor(dot, 2);
    if (sub == 0) s[k] = dot * 0.125f;
  }
  __syncthreads();
  float mx = -1e30f;
  for (int k = tid; k < NTOK; k += 256) mx = fmaxf(mx, s[k]);
  mx = blk_red_max(mx, red);
  float sm = 0.f;
  for (int k = tid; k < NTOK; k += 256) sm += expf(s[k] - mx);
  sm = blk_red_sum(sm, red);
  float inv = 1.f / sm;
  for (int k = tid; k < NTOK; k += 256)
    probs[(size_t)bh * NTOK + k] = expf(s[k] - mx) * inv;
}

// ---------------- top-k selection: one block per batch ----------------
__global__ __launch_bounds__(256) void topk_sel(const float* __restrict__ probs,
                                                const int* __restrict__ kpptr,
                                                int* __restrict__ topk) {
  __shared__ float accsc[NTOK];
  const int b = blockIdx.x, tid = threadIdx.x;
  for (int k = tid; k < NTOK; k += 256) {
    float a = 0.f;
#pragma unroll
    for (int h = 0; h < HEADS; ++h) a += probs[(size_t)(b * HEADS + h) * NTOK + k];
    accsc[k] = a;
  }
  __syncthreads();
  if (tid == 0) {
    int kpn = kpptr[0];
    if (kpn < 0) kpn = 0;
    if (kpn > 8) kpn = 8;
    for (int j = 0; j < kpn; ++j) {
      float best = -1e30f;
      int bi = 1;
      for (int k = 1; k < NTOK; ++k)
        if (accsc[k] > best) { best = accsc[k]; bi = k; }
      topk[b * 8 + j] = bi;
      accsc[bi] = -2e30f;
    }
    for (int j = kpn; j < 8; ++j) topk[b * 8 + j] = -1;
  }
}

// ---------------- MFMA attention (unchanged) ----------------
__device__ __forceinline__ bf16x8 pack8(float4 a, float4 b) {
  bf16x8 r;
  r[0] = (short)bf16r(a.x); r[1] = (short)bf16r(a.y);
  r[2] = (short)bf16r(a.z); r[3] = (short)bf16r(a.w);
  r[4] = (short)bf16r(b.x); r[5] = (short)bf16r(b.y);
  r[6] = (short)bf16r(b.z); r[7] = (short)bf16r(b.w);
  return r;
}

__global__ __launch_bounds__(512, 1) void attn_mfma(
    const float* __restrict__ qkv, const float* __restrict__ prompt_k,
    const float* __restrict__ prompt_v, const float* __restrict__ pk,
    const float* __restrict__ pv, const int* __restrict__ topk,
    const int* __restrict__ kpptr, u16* __restrict__ outp) {
  __shared__ u16 Ks[208 * 64];
  __shared__ u16 Vs[64 * 256];
  __shared__ u16 Ps[8][16 * 256];
  __shared__ float selb[NTOK];
  const int bh = blockIdx.x;
  const int b = bh / HEADS, h = bh % HEADS;
  const int tid = threadIdx.x, w = tid >> 6, lane = tid & 63;
  const int fr = lane & 15, lq = lane >> 4;

  int kpn = kpptr[0];
  if (kpn < 0) kpn = 0;
  if (kpn > 8) kpn = 8;
  for (int k = tid; k < NTOK; k += 512) {
    float sl = 0.f;
    for (int j = 0; j < kpn; ++j)
      if (topk[b * 8 + j] == k) sl = 1.f;
    selb[k] = sl;
  }
  __syncthreads();

  const size_t row0 = (size_t)b * NTOK * QKVD;
  const float* kg = qkv + row0 + DMODEL + h * HEADD;
  const float* vg = qkv + row0 + 2 * DMODEL + h * HEADD;
  for (int idx = tid; idx < 208 * 64; idx += 512) {
    int tok = idx >> 6, d = idx & 63;
    float v = 0.f;
    if (tok < NTOK) {
      v = kg[(size_t)tok * QKVD + d] + selb[tok] * pk[h * HEADD + d];
      if (tok == 0) v += prompt_k[h * HEADD + d];
    }
    int off = (tok * 128 + d * 2) ^ ((tok & 7) << 4);
    *(u16*)((char*)Ks + off) = bf16r(v);
  }
  for (int idx = tid; idx < 224 * 64; idx += 512) {
    int tok = idx >> 6, d = idx & 63;
    float v = 0.f;
    if (tok < NTOK) {
      v = vg[(size_t)tok * QKVD + d] + selb[tok] * pv[h * HEADD + d];
      if (tok == 0) v += prompt_v[h * HEADD + d];
    }
    int off = (d * 512 + tok * 2) ^ ((d & 7) << 4);
    *(u16*)((char*)Vs + off) = bf16r(v);
  }
  __syncthreads();

  u16* Pw = Ps[w];
  u16* ob = outp + (size_t)b * NTOK * DMODEL + h * HEADD;

#pragma unroll
  for (int pass = 0; pass < 2; ++pass) {
    const int qt = pass * 8 + w;
    const bool active = (qt < 14);
    if (active) {
      int qrow = qt * 16 + fr;
      if (qrow > NTOK - 1) qrow = NTOK - 1;
      const float* qp = qkv + row0 + (size_t)qrow * QKVD + h * HEADD + lq * 8;
      bf16x8 aq0 = pack8(*(const float4*)qp, *(const float4*)(qp + 4));
      bf16x8 aq1 = pack8(*(const float4*)(qp + 32), *(const float4*)(qp + 36));
      f32x4 sa[13];
#pragma unroll
      for (int j = 0; j < 13; ++j) {
        int tok = j * 16 + fr;
        int o0 = (tok * 128 + lq * 16) ^ ((tok & 7) << 4);
        int o1 = (tok * 128 + 64 + lq * 16) ^ ((tok & 7) << 4);
        bf16x8 bk0 = *(const bf16x8*)((const char*)Ks + o0);
        bf16x8 bk1 = *(const bf16x8*)((const char*)Ks + o1);
        f32x4 z = {0.f, 0.f, 0.f, 0.f};
        z = __builtin_amdgcn_mfma_f32_16x16x32_bf16(aq0, bk0, z, 0, 0, 0);
        sa[j] = __builtin_amdgcn_mfma_f32_16x16x32_bf16(aq1, bk1, z, 0, 0, 0);
      }
      const bool v12 = (fr < 5);
      float m4[4] = {-1e30f, -1e30f, -1e30f, -1e30f};
#pragma unroll
      for (int j = 0; j < 13; ++j) {
        if (j == 12 && !v12) continue;
#pragma unroll
        for (int r = 0; r < 4; ++r) m4[r] = fmaxf(m4[r], sa[j][r] * 0.125f);
      }
#pragma unroll
      for (int o = 8; o; o >>= 1)
#pragma unroll
        for (int r = 0; r < 4; ++r) m4[r] = fmaxf(m4[r], __shfl_xor(m4[r], o));
      float s4[4] = {0.f, 0.f, 0.f, 0.f};
#pragma unroll
      for (int j = 0; j < 13; ++j) {
        const bool valid = (j < 12) || v12;
#pragma unroll
        for (int r = 0; r < 4; ++r) {
          float p = valid ? __expf(sa[j][r] * 0.125f - m4[r]) : 0.f;
          sa[j][r] = p;
          s4[r] += p;
        }
      }
#pragma unroll
      for (int o = 8; o; o >>= 1)
#pragma unroll
        for (int r = 0; r < 4; ++r) s4[r] += __shfl_xor(s4[r], o);
      float inv[4];
#pragma unroll
      for (int r = 0; r < 4; ++r) inv[r] = 1.f / s4[r];
#pragma unroll
      for (int r = 0; r < 4; ++r) {
        int row = lq * 4 + r;
        int rbase = row * 512, sw = (row & 7) << 4;
#pragma unroll
        for (int j = 0; j < 13; ++j) {
          int off = (rbase + (j * 16 + fr) * 2) ^ sw;
          *(u16*)((char*)Pw + off) = bf16r(sa[j][r] * inv[r]);
        }
        int offz = (rbase + (208 + fr) * 2) ^ sw;
        *(u16*)((char*)Pw + offz) = 0;
      }
    }
    __syncthreads();
    if (active) {
      f32x4 oa[4] = {};
#pragma unroll
      for (int kc = 0; kc < 7; ++kc) {
        int po = (fr * 512 + (kc * 32 + lq * 8) * 2) ^ ((fr & 7) << 4);
        bf16x8 pa = *(const bf16x8*)((const char*)Pw + po);
#pragma unroll
        for (int dt = 0; dt < 4; ++dt) {
          int d = dt * 16 + fr;
          int vo = (d * 512 + (kc * 32 + lq * 8) * 2) ^ ((d & 7) << 4);
          bf16x8 vb = *(const bf16x8*)((const char*)Vs + vo);
          oa[dt] = __builtin_amdgcn_mfma_f32_16x16x32_bf16(pa, vb, oa[dt], 0, 0, 0);
        }
      }
#pragma unroll
      for (int r = 0; r < 4; ++r) {
        int q = qt * 16 + lq * 4 + r;
        if (q < NTOK) {
          u16* orow = ob + (size_t)q * DMODEL;
#pragma unroll
          for (int dt = 0; dt < 4; ++dt) orow[dt * 16 + fr] = bf16r(oa[dt][r]);
        }
      }
    }
    __syncthreads();
  }
}

// ---------------- host ----------------
extern "C" void kernel_launch(void* const* d_in, const int* in_sizes, int n_in,
                              void* d_out, int out_size, void* d_ws, size_t ws_size,
                              hipStream_t stream) {
  const float* x = (const float*)d_in[0];
  const float* patch_w = (const float*)d_in[1];
  const float* patch_b = (const float*)d_in[2];
  const float* cls_tok = (const float*)d_in[3];
  const float* pos_emb = (const float*)d_in[4];
  const float* ln1_w = (const float*)d_in[5];
  const float* ln1_b = (const float*)d_in[6];
  const float* qkv_w = (const float*)d_in[7];
  const float* qkv_b = (const float*)d_in[8];
  const float* proj_w = (const float*)d_in[9];
  const float* proj_b = (const float*)d_in[10];
  const float* pk_par = (const float*)d_in[11];
  const float* pv_par = (const float*)d_in[12];
  const float* pr_k = (const float*)d_in[13];
  const float* pr_v = (const float*)d_in[14];
  const float* ln2_w = (const float*)d_in[15];
  const float* ln2_b = (const float*)d_in[16];
  const float* fc1_w = (const float*)d_in[17];
  const float* fc1_b = (const float*)d_in[18];
  const float* fc2_w = (const float*)d_in[19];
  const float* fc2_b = (const float*)d_in[20];
  const float* norm_w = (const float*)d_in[21];
  const float* norm_b = (const float*)d_in[22];
  const int* kp = (const int*)d_in[23];

  float* tokens = (float*)d_ws;
  float* bufh = tokens + (size_t)MTOK * DMODEL;
  float* bufbig = bufh + (size_t)MTOK * DMODEL;
  u16* wbuf = (u16*)(bufbig + (size_t)MTOK * MLPD);
  u16* im2colb = wbuf + WTOTAL;
  int* topk = (int*)(im2colb + (size_t)MPAT * DMODEL);
  float* probs = (float*)(topk + BATCH * 8);

  const int mt = (MTOK + 127) / 128;   // 50
  const int mtp = (MPAT + 127) / 128;  // 49

  convert_bf16<<<(DMODEL * DMODEL / 4 + 255) / 256, 256, 0, stream>>>(
      patch_w, wbuf, DMODEL * DMODEL);
  im2col<<<(MPAT * DMODEL + 255) / 256, 256, 0, stream>>>(x, im2colb);
  gemm3<0, 64><<<dim3(mtp, DMODEL / 64), 256, 0, stream>>>(
      im2colb, wbuf, patch_b, bufh, MPAT, DMODEL, DMODEL);
  assemble<<<(MTOK * DMODEL + 255) / 256, 256, 0, stream>>>(bufh, cls_tok,
                                                            pos_emb, tokens);

  for (int l = 0; l < DEPTH; ++l) {
    convert_layer_w<<<(WTOTAL / 4 + 255) / 256, 256, 0, stream>>>(
        qkv_w + (size_t)l * QKVD * DMODEL, proj_w + (size_t)l * DMODEL * DMODEL,
        fc1_w + (size_t)l * MLPD * DMODEL, fc2_w + (size_t)l * DMODEL * MLPD,
        wbuf);
    layernorm<true><<<MTOK, 256, 0, stream>>>(tokens, ln1_w + l * DMODEL,
                                              ln1_b + l * DMODEL, bufh);
    gemm3<0, 128><<<dim3(mt, QKVD / 128), 256, 0, stream>>>(
        (const u16*)bufh, wbuf + OFF_QKV, qkv_b + l * QKVD, bufbig,
        MTOK, QKVD, DMODEL);
    probe_scores<<<BATCH * HEADS, 256, 0, stream>>>(bufbig, probs);
    topk_sel<<<BATCH, 256, 0, stream>>>(probs, kp, topk);
    attn_mfma<<<BATCH * HEADS, 512, 0, stream>>>(
        bufbig, pr_k + l * HEADS * HEADD, pr_v + l * HEADS * HEADD,
        pk_par + l * HEADS * HEADD, pv_par + l * HEADS * HEADD, topk, kp,
        (u16*)bufh);
    gemm3<1, 64><<<dim3(mt, DMODEL / 64), 256, 0, stream>>>(
        (const u16*)bufh, wbuf + OFF_PROJ, proj_b + l * DMODEL, tokens,
        MTOK, DMODEL, DMODEL);
    layernorm<true><<<MTOK, 256, 0, stream>>>(tokens, ln2_w + l * DMODEL,
                                              ln2_b + l * DMODEL, bufh);
    gemm3<2, 128><<<dim3(mt, MLPD / 128), 256, 0, stream>>>(
        (const u16*)bufh, wbuf + OFF_FC1, fc1_b + l * MLPD, bufbig,
        MTOK, MLPD, DMODEL);
    gemm3<1, 64><<<dim3(mt, DMODEL / 64), 256, 0, stream>>>(
        (const u16*)bufbig, wbuf + OFF_FC2, fc2_b + l * DMODEL, tokens,
        MTOK, DMODEL, MLPD);
  }
  layernorm<false><<<MTOK, 256, 0, stream>>>(tokens, norm_w, norm_b, d_out);
}

// Round 6
// 3863.496 us; speedup vs baseline: 5.2689x; 1.0759x over previous
//
#include <hip/hip_runtime.h>
#include <math.h>

#define DMODEL 768
#define DEPTH 12
#define HEADS 12
#define HEADD 64
#define NTOK 197
#define BATCH 32
#define NPATCH 196
#define MTOK (BATCH * NTOK)    // 6304
#define MPAT (BATCH * NPATCH)  // 6272
#define QKVD 2304
#define MLPD 3072

typedef unsigned short u16;
typedef __attribute__((ext_vector_type(8))) short bf16x8;
typedef __attribute__((ext_vector_type(4))) float f32x4;

#define OFF_QKV 0
#define OFF_PROJ (QKVD * DMODEL)
#define OFF_FC1 (OFF_PROJ + DMODEL * DMODEL)
#define OFF_FC2 (OFF_FC1 + MLPD * DMODEL)
#define WTOTAL (OFF_FC2 + DMODEL * MLPD)

__device__ __forceinline__ u16 bf16r(float x) {
  union { float f; unsigned u; } c; c.f = x;
  unsigned u = c.u + 0x7FFF + ((c.u >> 16) & 1);
  return (u16)(u >> 16);
}
__device__ __forceinline__ float gelu_f(float x) {
  return 0.5f * x * (1.f + erff(x * 0.70710678118654752440f));
}
__device__ __forceinline__ void gload16(const void* g, void* l) {
  __builtin_amdgcn_global_load_lds(
      (const __attribute__((address_space(1))) void*)g,
      (__attribute__((address_space(3))) void*)l, 16, 0, 0);
}

// ---------------- block-wide reductions ----------------
__device__ __forceinline__ float blk_red_sum(float v, float* red) {
#pragma unroll
  for (int o = 32; o; o >>= 1) v += __shfl_xor(v, o);
  __syncthreads();
  if ((threadIdx.x & 63) == 0) red[threadIdx.x >> 6] = v;
  __syncthreads();
  return red[0] + red[1] + red[2] + red[3];
}
__device__ __forceinline__ float blk_red_max(float v, float* red) {
#pragma unroll
  for (int o = 32; o; o >>= 1) v = fmaxf(v, __shfl_xor(v, o));
  __syncthreads();
  if ((threadIdx.x & 63) == 0) red[threadIdx.x >> 6] = v;
  __syncthreads();
  return fmaxf(fmaxf(red[0], red[1]), fmaxf(red[2], red[3]));
}

// ---------------- f32 -> bf16 conversions ----------------
__global__ __launch_bounds__(256) void convert_bf16(const float* __restrict__ in,
                                                    u16* __restrict__ out, int n) {
  int i = (blockIdx.x * 256 + threadIdx.x) * 4;
  if (i >= n) return;
  float4 v = *(const float4*)(in + i);
  ushort4 o;
  o.x = bf16r(v.x); o.y = bf16r(v.y); o.z = bf16r(v.z); o.w = bf16r(v.w);
  *(ushort4*)(out + i) = o;
}

__global__ __launch_bounds__(256) void convert_layer_w(
    const float* __restrict__ qkv_w, const float* __restrict__ proj_w,
    const float* __restrict__ fc1_w, const float* __restrict__ fc2_w,
    u16* __restrict__ wbuf) {
  int i = (blockIdx.x * 256 + threadIdx.x) * 4;
  if (i >= WTOTAL) return;
  const float* s;
  if (i < OFF_PROJ) s = qkv_w + i;
  else if (i < OFF_FC1) s = proj_w + (i - OFF_PROJ);
  else if (i < OFF_FC2) s = fc1_w + (i - OFF_FC1);
  else s = fc2_w + (i - OFF_FC2);
  float4 v = *(const float4*)s;
  ushort4 o;
  o.x = bf16r(v.x); o.y = bf16r(v.y); o.z = bf16r(v.z); o.w = bf16r(v.w);
  *(ushort4*)(wbuf + i) = o;
}

// ---------------- im2col (bf16 out) ----------------
__global__ __launch_bounds__(256) void im2col(const float* __restrict__ x,
                                              u16* __restrict__ col) {
  int idx = blockIdx.x * 256 + threadIdx.x;
  if (idx >= MPAT * DMODEL) return;
  int kk = idx % DMODEL;
  int m = idx / DMODEL;
  int bb = m / NPATCH, p = m % NPATCH;
  int ph = p / 14, pw = p % 14;
  int ch = kk >> 8, rem = kk & 255;
  int i = rem >> 4, j = rem & 15;
  col[idx] = bf16r(x[(((size_t)bb * 3 + ch) * 224 + ph * 16 + i) * 224 + pw * 16 + j]);
}

// ---------------- token assembly ----------------
__global__ __launch_bounds__(256) void assemble(const float* __restrict__ pat,
                                                const float* __restrict__ cls,
                                                const float* __restrict__ pos,
                                                float* __restrict__ tokens) {
  int idx = blockIdx.x * 256 + threadIdx.x;
  if (idx >= MTOK * DMODEL) return;
  int c = idx % DMODEL;
  int t = idx / DMODEL;
  int bb = t / NTOK, n = t % NTOK;
  float v;
  if (n == 0) v = cls[c];
  else v = pat[((size_t)bb * NPATCH + (n - 1)) * DMODEL + c];
  tokens[idx] = v + pos[n * DMODEL + c];
}

// ---------------- LayerNorm ----------------
template <bool BF16OUT>
__global__ __launch_bounds__(256) void layernorm(const float* __restrict__ in,
                                                 const float* __restrict__ w,
                                                 const float* __restrict__ b,
                                                 void* __restrict__ outp) {
  __shared__ float red[4];
  const int t = blockIdx.x, tid = threadIdx.x;
  const float* r = in + (size_t)t * DMODEL;
  float x0 = r[tid], x1 = r[tid + 256], x2 = r[tid + 512];
  float mu = blk_red_sum(x0 + x1 + x2, red) * (1.f / 768.f);
  float d0 = x0 - mu, d1 = x1 - mu, d2 = x2 - mu;
  float var = blk_red_sum(d0 * d0 + d1 * d1 + d2 * d2, red) * (1.f / 768.f);
  float is = rsqrtf(var + 1e-6f);
  float v0 = d0 * is * w[tid] + b[tid];
  float v1 = d1 * is * w[tid + 256] + b[tid + 256];
  float v2 = d2 * is * w[tid + 512] + b[tid + 512];
  if (BF16OUT) {
    u16* o = (u16*)outp + (size_t)t * DMODEL;
    o[tid] = bf16r(v0); o[tid + 256] = bf16r(v1); o[tid + 512] = bf16r(v2);
  } else {
    float* o = (float*)outp + (size_t)t * DMODEL;
    o[tid] = v0; o[tid + 256] = v1; o[tid + 512] = v2;
  }
}

// ------- bf16 MFMA NT GEMM: 3-buffer, 2-ahead prefetch, counted vmcnt -------
// Tile 128 x TN, BK=32, 4 waves. Chunk swizzle key = (row>>1)&3 (row pitch
// 64B = 16 banks, rows alias mod 2 -> key must use row bits >= 1). Global
// source pre-swizzled, LDS dest linear (rule #21), read applies same XOR.
// Block ordering: n-fastest within XCD chunk (A-panel L2 reuse).
// MODE 0: C(f32)=acc+bias ; 1: C(f32)+=acc+bias ; 2: C(bf16)=gelu(acc+bias)
template <int MODE, int TN>
__global__ __launch_bounds__(256) void gemm3(const u16* __restrict__ A,
                                             const u16* __restrict__ B,
                                             const float* __restrict__ bias,
                                             void* __restrict__ C,
                                             int M, int N, int K) {
  constexpr int NJ = TN / 32;
  constexpr int LPT = (TN == 128) ? 4 : 3;  // gload16 per wave per tile
  __shared__ u16 As[3][128 * 32];
  __shared__ u16 Bs[3][TN * 32];
  const int tid = threadIdx.x;
  const int w = tid >> 6, lane = tid & 63;

  // bijective XCD-chunked swizzle (m204)
  const int nwg = gridDim.x * gridDim.y;
  int lin = blockIdx.y * gridDim.x + blockIdx.x;
  {
    int q = nwg >> 3, r = nwg & 7;
    int xcd = lin & 7, idx = lin >> 3;
    lin = (xcd < r ? xcd * (q + 1) : r * (q + 1) + (xcd - r) * q) + idx;
  }
  const int ntn = gridDim.y;  // n-tiles
  const int m0 = (lin / ntn) * 128, n0 = (lin % ntn) * TN;  // n-fastest

  const int wr = (w >> 1) * 64, wc = (w & 1) * (TN / 2);
  f32x4 acc[4][NJ] = {};

  // staging: thread t -> row t/4 within 64-row half; global chunk pre-swizzled
  const int srow = tid >> 2;
  const int scol = ((tid & 3) ^ ((srow >> 1) & 3)) * 8;
  int ar0 = m0 + srow;       if (ar0 >= M) ar0 = M - 1;
  int ar1 = m0 + 64 + srow;  if (ar1 >= M) ar1 = M - 1;
  const u16* Ag0 = A + (size_t)ar0 * K + scol;
  const u16* Ag1 = A + (size_t)ar1 * K + scol;
  const u16* Bg0 = B + (size_t)(n0 + srow) * K + scol;
  const u16* Bg1 = B + (size_t)(n0 + (TN == 128 ? 64 : 0) + srow) * K + scol;

  auto STAGE = [&](int buf, int kk) {
    gload16(Ag0 + kk, &As[buf][w * 512]);
    gload16(Ag1 + kk, &As[buf][2048 + w * 512]);
    gload16(Bg0 + kk, &Bs[buf][w * 512]);
    if (TN == 128) gload16(Bg1 + kk, &Bs[buf][2048 + w * 512]);
  };

  const int fr = lane & 15, lq = lane >> 4;
  const int kq = (lq ^ ((fr >> 1) & 3)) * 8;  // same XOR on the read side

  const int nt = K >> 5;
  STAGE(0, 0);
  STAGE(1, 32);
  asm volatile("s_waitcnt vmcnt(%0)" ::"n"(LPT) : "memory");
  __builtin_amdgcn_s_barrier();
  __builtin_amdgcn_sched_barrier(0);

  for (int t = 0; t < nt; ++t) {
    const int cur = t % 3;
    bf16x8 af[4], bfr[NJ];
#pragma unroll
    for (int i = 0; i < 4; ++i)
      af[i] = *(const bf16x8*)&As[cur][(wr + i * 16 + fr) * 32 + kq];
#pragma unroll
    for (int j = 0; j < NJ; ++j)
      bfr[j] = *(const bf16x8*)&Bs[cur][(wc + j * 16 + fr) * 32 + kq];
    const bool more = (t + 2 < nt);
    if (more) STAGE((t + 2) % 3, (t + 2) * 32);
#pragma unroll
    for (int i = 0; i < 4; ++i)
#pragma unroll
      for (int j = 0; j < NJ; ++j)
        acc[i][j] = __builtin_amdgcn_mfma_f32_16x16x32_bf16(af[i], bfr[j],
                                                            acc[i][j], 0, 0, 0);
    if (more)
      asm volatile("s_waitcnt vmcnt(%0)" ::"n"(LPT) : "memory");
    else
      asm volatile("s_waitcnt vmcnt(0)" ::: "memory");
    __builtin_amdgcn_s_barrier();
    __builtin_amdgcn_sched_barrier(0);
  }

  const int fq = lq * 4;
#pragma unroll
  for (int j = 0; j < NJ; ++j) {
    const int n = n0 + wc + j * 16 + fr;
    const float bb = bias[n];
#pragma unroll
    for (int i = 0; i < 4; ++i) {
      const int mbase = m0 + wr + i * 16 + fq;
#pragma unroll
      for (int r = 0; r < 4; ++r) {
        const int m = mbase + r;
        if (m < M) {
          const float v = acc[i][j][r] + bb;
          if (MODE == 0) ((float*)C)[(size_t)m * N + n] = v;
          else if (MODE == 1) ((float*)C)[(size_t)m * N + n] += v;
          else ((u16*)C)[(size_t)m * N + n] = bf16r(gelu_f(v));
        }
      }
    }
  }
}

// ---------------- probe scores: one block per (b,h) ----------------
__global__ __launch_bounds__(256) void probe_scores(const float* __restrict__ qkv,
                                                    float* __restrict__ probs) {
  __shared__ float qrow[64];
  __shared__ float s[NTOK];
  __shared__ float red[4];
  const int bh = blockIdx.x;
  const int b = bh / HEADS, h = bh % HEADS;
  const int tid = threadIdx.x;
  const size_t row0 = (size_t)b * NTOK * QKVD;
  if (tid < 64) qrow[tid] = qkv[row0 + h * HEADD + tid];
  __syncthreads();
  const int sub = tid & 3;
  for (int k = tid >> 2; k < NTOK; k += 64) {
    const float* kr = qkv + row0 + (size_t)k * QKVD + DMODEL + h * HEADD + sub * 16;
    float dot = 0.f;
#pragma unroll
    for (int c = 0; c < 4; ++c) {
      float4 kv = *(const float4*)(kr + c * 4);
      dot = fmaf(qrow[sub * 16 + c * 4 + 0], kv.x, dot);
      dot = fmaf(qrow[sub * 16 + c * 4 + 1], kv.y, dot);
      dot = fmaf(qrow[sub * 16 + c * 4 + 2], kv.z, dot);
      dot = fmaf(qrow[sub * 16 + c * 4 + 3], kv.w, dot);
    }
    dot += __shfl_xor(dot, 1);
    dot += __shfl_xor(dot, 2);
    if (sub == 0) s[k] = dot * 0.125f;
  }
  __syncthreads();
  float mx = -1e30f;
  for (int k = tid; k < NTOK; k += 256) mx = fmaxf(mx, s[k]);
  mx = blk_red_max(mx, red);
  float sm = 0.f;
  for (int k = tid; k < NTOK; k += 256) sm += expf(s[k] - mx);
  sm = blk_red_sum(sm, red);
  float inv = 1.f / sm;
  for (int k = tid; k < NTOK; k += 256)
    probs[(size_t)bh * NTOK + k] = expf(s[k] - mx) * inv;
}

// ---------------- top-k selection: one block per batch ----------------
__global__ __launch_bounds__(256) void topk_sel(const float* __restrict__ probs,
                                                const int* __restrict__ kpptr,
                                                int* __restrict__ topk) {
  __shared__ float accsc[NTOK];
  const int b = blockIdx.x, tid = threadIdx.x;
  for (int k = tid; k < NTOK; k += 256) {
    float a = 0.f;
#pragma unroll
    for (int h = 0; h < HEADS; ++h) a += probs[(size_t)(b * HEADS + h) * NTOK + k];
    accsc[k] = a;
  }
  __syncthreads();
  if (tid == 0) {
    int kpn = kpptr[0];
    if (kpn < 0) kpn = 0;
    if (kpn > 8) kpn = 8;
    for (int j = 0; j < kpn; ++j) {
      float best = -1e30f;
      int bi = 1;
      for (int k = 1; k < NTOK; ++k)
        if (accsc[k] > best) { best = accsc[k]; bi = k; }
      topk[b * 8 + j] = bi;
      accsc[bi] = -2e30f;
    }
    for (int j = kpn; j < 8; ++j) topk[b * 8 + j] = -1;
  }
}

// ---------------- MFMA attention (unchanged) ----------------
__device__ __forceinline__ bf16x8 pack8(float4 a, float4 b) {
  bf16x8 r;
  r[0] = (short)bf16r(a.x); r[1] = (short)bf16r(a.y);
  r[2] = (short)bf16r(a.z); r[3] = (short)bf16r(a.w);
  r[4] = (short)bf16r(b.x); r[5] = (short)bf16r(b.y);
  r[6] = (short)bf16r(b.z); r[7] = (short)bf16r(b.w);
  return r;
}

__global__ __launch_bounds__(512, 1) void attn_mfma(
    const float* __restrict__ qkv, const float* __restrict__ prompt_k,
    const float* __restrict__ prompt_v, const float* __restrict__ pk,
    const float* __restrict__ pv, const int* __restrict__ topk,
    const int* __restrict__ kpptr, u16* __restrict__ outp) {
  __shared__ u16 Ks[208 * 64];
  __shared__ u16 Vs[64 * 256];
  __shared__ u16 Ps[8][16 * 256];
  __shared__ float selb[NTOK];
  const int bh = blockIdx.x;
  const int b = bh / HEADS, h = bh % HEADS;
  const int tid = threadIdx.x, w = tid >> 6, lane = tid & 63;
  const int fr = lane & 15, lq = lane >> 4;

  int kpn = kpptr[0];
  if (kpn < 0) kpn = 0;
  if (kpn > 8) kpn = 8;
  for (int k = tid; k < NTOK; k += 512) {
    float sl = 0.f;
    for (int j = 0; j < kpn; ++j)
      if (topk[b * 8 + j] == k) sl = 1.f;
    selb[k] = sl;
  }
  __syncthreads();

  const size_t row0 = (size_t)b * NTOK * QKVD;
  const float* kg = qkv + row0 + DMODEL + h * HEADD;
  const float* vg = qkv + row0 + 2 * DMODEL + h * HEADD;
  for (int idx = tid; idx < 208 * 64; idx += 512) {
    int tok = idx >> 6, d = idx & 63;
    float v = 0.f;
    if (tok < NTOK) {
      v = kg[(size_t)tok * QKVD + d] + selb[tok] * pk[h * HEADD + d];
      if (tok == 0) v += prompt_k[h * HEADD + d];
    }
    int off = (tok * 128 + d * 2) ^ ((tok & 7) << 4);
    *(u16*)((char*)Ks + off) = bf16r(v);
  }
  for (int idx = tid; idx < 224 * 64; idx += 512) {
    int tok = idx >> 6, d = idx & 63;
    float v = 0.f;
    if (tok < NTOK) {
      v = vg[(size_t)tok * QKVD + d] + selb[tok] * pv[h * HEADD + d];
      if (tok == 0) v += prompt_v[h * HEADD + d];
    }
    int off = (d * 512 + tok * 2) ^ ((d & 7) << 4);
    *(u16*)((char*)Vs + off) = bf16r(v);
  }
  __syncthreads();

  u16* Pw = Ps[w];
  u16* ob = outp + (size_t)b * NTOK * DMODEL + h * HEADD;

#pragma unroll
  for (int pass = 0; pass < 2; ++pass) {
    const int qt = pass * 8 + w;
    const bool active = (qt < 14);
    if (active) {
      int qrow = qt * 16 + fr;
      if (qrow > NTOK - 1) qrow = NTOK - 1;
      const float* qp = qkv + row0 + (size_t)qrow * QKVD + h * HEADD + lq * 8;
      bf16x8 aq0 = pack8(*(const float4*)qp, *(const float4*)(qp + 4));
      bf16x8 aq1 = pack8(*(const float4*)(qp + 32), *(const float4*)(qp + 36));
      f32x4 sa[13];
#pragma unroll
      for (int j = 0; j < 13; ++j) {
        int tok = j * 16 + fr;
        int o0 = (tok * 128 + lq * 16) ^ ((tok & 7) << 4);
        int o1 = (tok * 128 + 64 + lq * 16) ^ ((tok & 7) << 4);
        bf16x8 bk0 = *(const bf16x8*)((const char*)Ks + o0);
        bf16x8 bk1 = *(const bf16x8*)((const char*)Ks + o1);
        f32x4 z = {0.f, 0.f, 0.f, 0.f};
        z = __builtin_amdgcn_mfma_f32_16x16x32_bf16(aq0, bk0, z, 0, 0, 0);
        sa[j] = __builtin_amdgcn_mfma_f32_16x16x32_bf16(aq1, bk1, z, 0, 0, 0);
      }
      const bool v12 = (fr < 5);
      float m4[4] = {-1e30f, -1e30f, -1e30f, -1e30f};
#pragma unroll
      for (int j = 0; j < 13; ++j) {
        if (j == 12 && !v12) continue;
#pragma unroll
        for (int r = 0; r < 4; ++r) m4[r] = fmaxf(m4[r], sa[j][r] * 0.125f);
      }
#pragma unroll
      for (int o = 8; o; o >>= 1)
#pragma unroll
        for (int r = 0; r < 4; ++r) m4[r] = fmaxf(m4[r], __shfl_xor(m4[r], o));
      float s4[4] = {0.f, 0.f, 0.f, 0.f};
#pragma unroll
      for (int j = 0; j < 13; ++j) {
        const bool valid = (j < 12) || v12;
#pragma unroll
        for (int r = 0; r < 4; ++r) {
          float p = valid ? __expf(sa[j][r] * 0.125f - m4[r]) : 0.f;
          sa[j][r] = p;
          s4[r] += p;
        }
      }
#pragma unroll
      for (int o = 8; o; o >>= 1)
#pragma unroll
        for (int r = 0; r < 4; ++r) s4[r] += __shfl_xor(s4[r], o);
      float inv[4];
#pragma unroll
      for (int r = 0; r < 4; ++r) inv[r] = 1.f / s4[r];
#pragma unroll
      for (int r = 0; r < 4; ++r) {
        int row = lq * 4 + r;
        int rbase = row * 512, sw = (row & 7) << 4;
#pragma unroll
        for (int j = 0; j < 13; ++j) {
          int off = (rbase + (j * 16 + fr) * 2) ^ sw;
          *(u16*)((char*)Pw + off) = bf16r(sa[j][r] * inv[r]);
        }
        int offz = (rbase + (208 + fr) * 2) ^ sw;
        *(u16*)((char*)Pw + offz) = 0;
      }
    }
    __syncthreads();
    if (active) {
      f32x4 oa[4] = {};
#pragma unroll
      for (int kc = 0; kc < 7; ++kc) {
        int po = (fr * 512 + (kc * 32 + lq * 8) * 2) ^ ((fr & 7) << 4);
        bf16x8 pa = *(const bf16x8*)((const char*)Pw + po);
#pragma unroll
        for (int dt = 0; dt < 4; ++dt) {
          int d = dt * 16 + fr;
          int vo = (d * 512 + (kc * 32 + lq * 8) * 2) ^ ((d & 7) << 4);
          bf16x8 vb = *(const bf16x8*)((const char*)Vs + vo);
          oa[dt] = __builtin_amdgcn_mfma_f32_16x16x32_bf16(pa, vb, oa[dt], 0, 0, 0);
        }
      }
#pragma unroll
      for (int r = 0; r < 4; ++r) {
        int q = qt * 16 + lq * 4 + r;
        if (q < NTOK) {
          u16* orow = ob + (size_t)q * DMODEL;
#pragma unroll
          for (int dt = 0; dt < 4; ++dt) orow[dt * 16 + fr] = bf16r(oa[dt][r]);
        }
      }
    }
    __syncthreads();
  }
}

// ---------------- host ----------------
extern "C" void kernel_launch(void* const* d_in, const int* in_sizes, int n_in,
                              void* d_out, int out_size, void* d_ws, size_t ws_size,
                              hipStream_t stream) {
  const float* x = (const float*)d_in[0];
  const float* patch_w = (const float*)d_in[1];
  const float* patch_b = (const float*)d_in[2];
  const float* cls_tok = (const float*)d_in[3];
  const float* pos_emb = (const float*)d_in[4];
  const float* ln1_w = (const float*)d_in[5];
  const float* ln1_b = (const float*)d_in[6];
  const float* qkv_w = (const float*)d_in[7];
  const float* qkv_b = (const float*)d_in[8];
  const float* proj_w = (const float*)d_in[9];
  const float* proj_b = (const float*)d_in[10];
  const float* pk_par = (const float*)d_in[11];
  const float* pv_par = (const float*)d_in[12];
  const float* pr_k = (const float*)d_in[13];
  const float* pr_v = (const float*)d_in[14];
  const float* ln2_w = (const float*)d_in[15];
  const float* ln2_b = (const float*)d_in[16];
  const float* fc1_w = (const float*)d_in[17];
  const float* fc1_b = (const float*)d_in[18];
  const float* fc2_w = (const float*)d_in[19];
  const float* fc2_b = (const float*)d_in[20];
  const float* norm_w = (const float*)d_in[21];
  const float* norm_b = (const float*)d_in[22];
  const int* kp = (const int*)d_in[23];

  float* tokens = (float*)d_ws;
  float* bufh = tokens + (size_t)MTOK * DMODEL;
  float* bufbig = bufh + (size_t)MTOK * DMODEL;
  u16* wbuf = (u16*)(bufbig + (size_t)MTOK * MLPD);
  u16* im2colb = wbuf + WTOTAL;
  int* topk = (int*)(im2colb + (size_t)MPAT * DMODEL);
  float* probs = (float*)(topk + BATCH * 8);

  const int mt = (MTOK + 127) / 128;   // 50
  const int mtp = (MPAT + 127) / 128;  // 49

  convert_bf16<<<(DMODEL * DMODEL / 4 + 255) / 256, 256, 0, stream>>>(
      patch_w, wbuf, DMODEL * DMODEL);
  im2col<<<(MPAT * DMODEL + 255) / 256, 256, 0, stream>>>(x, im2colb);
  gemm3<0, 64><<<dim3(mtp, DMODEL / 64), 256, 0, stream>>>(
      im2colb, wbuf, patch_b, bufh, MPAT, DMODEL, DMODEL);
  assemble<<<(MTOK * DMODEL + 255) / 256, 256, 0, stream>>>(bufh, cls_tok,
                                                            pos_emb, tokens);

  for (int l = 0; l < DEPTH; ++l) {
    convert_layer_w<<<(WTOTAL / 4 + 255) / 256, 256, 0, stream>>>(
        qkv_w + (size_t)l * QKVD * DMODEL, proj_w + (size_t)l * DMODEL * DMODEL,
        fc1_w + (size_t)l * MLPD * DMODEL, fc2_w + (size_t)l * DMODEL * MLPD,
        wbuf);
    layernorm<true><<<MTOK, 256, 0, stream>>>(tokens, ln1_w + l * DMODEL,
                                              ln1_b + l * DMODEL, bufh);
    gemm3<0, 128><<<dim3(mt, QKVD / 128), 256, 0, stream>>>(
        (const u16*)bufh, wbuf + OFF_QKV, qkv_b + l * QKVD, bufbig,
        MTOK, QKVD, DMODEL);
    probe_scores<<<BATCH * HEADS, 256, 0, stream>>>(bufbig, probs);
    topk_sel<<<BATCH, 256, 0, stream>>>(probs, kp, topk);
    attn_mfma<<<BATCH * HEADS, 512, 0, stream>>>(
        bufbig, pr_k + l * HEADS * HEADD, pr_v + l * HEADS * HEADD,
        pk_par + l * HEADS * HEADD, pv_par + l * HEADS * HEADD, topk, kp,
        (u16*)bufh);
    gemm3<1, 64><<<dim3(mt, DMODEL / 64), 256, 0, stream>>>(
        (const u16*)bufh, wbuf + OFF_PROJ, proj_b + l * DMODEL, tokens,
        MTOK, DMODEL, DMODEL);
    layernorm<true><<<MTOK, 256, 0, stream>>>(tokens, ln2_w + l * DMODEL,
                                              ln2_b + l * DMODEL, bufh);
    gemm3<2, 128><<<dim3(mt, MLPD / 128), 256, 0, stream>>>(
        (const u16*)bufh, wbuf + OFF_FC1, fc1_b + l * MLPD, bufbig,
        MTOK, MLPD, DMODEL);
    gemm3<1, 64><<<dim3(mt, DMODEL / 64), 256, 0, stream>>>(
        (const u16*)bufbig, wbuf + OFF_FC2, fc2_b + l * DMODEL, tokens,
        MTOK, DMODEL, MLPD);
  }
  layernorm<false><<<MTOK, 256, 0, stream>>>(tokens, norm_w, norm_b, d_out);
}